// Round 9
// baseline (4675.199 us; speedup 1.0000x reference)
//
#include <hip/hip_runtime.h>
#include <stdint.h>

#define Bsz  128
#define NUMS 128
#define SEQn 256
#define Hn   1024
#define PRED 96
#define G4H  4096
#define GN   256            // persistent grid: 256 blocks = 64 nb x 4 mb (1 per CU)
#define BH   ((size_t)Bsz*Hn)

typedef __attribute__((ext_vector_type(8))) short bf16x8;
typedef __attribute__((ext_vector_type(4))) float f32x4;

template<int N> struct IC { static constexpr int value = N; };

__device__ __forceinline__ unsigned short f2bf(float x){
  union { float f; unsigned u; } v; v.f = x;
  return (unsigned short)((v.u + 0x7FFFu + ((v.u >> 16) & 1u)) >> 16);
}

// ---- pack x: [B][NUMS][SEQ] f32 -> xp [SEQ][B][NUMS] bf16 (LDS transpose) ----
__global__ void pack_x_kernel(const float* __restrict__ x, unsigned short* __restrict__ xp){
  __shared__ float tile[64][65];
  const int t0 = blockIdx.x * 64, n0 = blockIdx.y * 64, b = blockIdx.z;
  const int tid = threadIdx.x;
  const int c = tid & 63, r = tid >> 6;
  #pragma unroll
  for (int i = 0; i < 16; i++){
    int n = r + i*4;
    tile[n][c] = x[((size_t)b*NUMS + n0 + n)*SEQn + t0 + c];
  }
  __syncthreads();
  #pragma unroll
  for (int i = 0; i < 16; i++){
    int t = r + i*4;
    xp[((size_t)(t0+t)*Bsz + b)*NUMS + n0 + c] = f2bf(tile[c][t]);
  }
}

// ---- pack W rows into MFMA B-frag order: Wpk[cgg][kof+kst][lane][8] ----
__global__ void pack_w_kernel(const float* __restrict__ W, unsigned short* __restrict__ Wpk,
                              int KST, int row_off, int kstride, int kof){
  const int u = blockIdx.x * blockDim.x + threadIdx.x;
  if (u >= 256*KST*64) return;
  const int lane = u & 63;
  const int kst  = (u >> 6) % KST;
  const int cgg  = (u >> 6) / KST;
  const int nb = cgg >> 2, gate = cgg & 3;
  const int col = gate*Hn + nb*16 + (lane & 15);
  const int kbase = row_off + kst*32 + (lane >> 4)*8;
  unsigned short tmp[8];
  #pragma unroll
  for (int e = 0; e < 8; e++) tmp[e] = f2bf(W[(size_t)(kbase+e)*G4H + col]);
  ((ulonglong2*)Wpk)[(size_t)(cgg*kstride + kof + kst)*64 + lane] = *(const ulonglong2*)tmp;
}

__global__ void zero_kernel(unsigned short* __restrict__ h0, float* __restrict__ c,
                            unsigned* __restrict__ bars){
  int i = blockIdx.x*256 + threadIdx.x;
  if (i < Bsz*Hn){ h0[i] = 0; c[i] = 0.0f; }
  if (i < 2048) bars[i] = 0u;
}

// ---- persistent LSTM layer, W resident in AGPRs across all 256 steps ----
// grid = 256 blocks (1/CU), 512 thr = 8 waves = 4 gates x 2 K-parities.
// Per-wave W: KST_TOT/2 bf16x8 frags = 72 (L0) / 128 (L1) regs. Round-7 lesson:
// "+v" keepalive forced VGPR placement -> allocator spilled to scratch (VGPR=116
// < 128 needed). Fix: "+a" keepalive -> W occupies the AGPR half of the unified
// gfx950 register file (MFMA reads B directly from AGPR, ISA §10). All wreg
// indices compile-time (tagged-lambda chunk expansion).
// K layout: [region1: h, stride K1=1024] [region2: stride S2].
//   LAYER=0: region1 = h0_{t-1} (ring slot t), region2 = xp_t (static input,
//            prefetched under the barrier into xb).
//   LAYER=1: region1 = h0_t (ring slot t+1, stable -> in-barrier prefetch),
//            region2 = h1_{t-1} (RING2: write-once ring; else aux=17 ping-pong).
// Barrier: dependency-exact per-(t,mb) 64-arrival counter (block (nb,mb) only
// consumes rows produced by same-mb blocks). c lives in ONE register per thread.
template<int K1, int S2, int KTOT, int LAYER, bool RING2>
__global__ __launch_bounds__(512, 2)
void persist_kernel(const unsigned short* __restrict__ xpp,
                    unsigned short* __restrict__ hring,
                    unsigned short* __restrict__ h1b,
                    const unsigned short* __restrict__ Wpk,
                    const float* __restrict__ bias,
                    float* __restrict__ cst,
                    float* __restrict__ hf_out,
                    unsigned* __restrict__ bar)
{
  constexpr int KST_TOT = KTOT/32;
  constexpr int HALF = KST_TOT/2;
  constexpr int NCH = (KTOT + 511)/512;
  __shared__ union SM {
    struct { unsigned short a[2][32*512]; unsigned short xb[32*128]; } s;  // 64KB + 8KB
    float e[2][4*32*18];                                                   // 18.4KB overlay
  } sm;
  const int tid = threadIdx.x;
  const int w = tid >> 6, l = tid & 63;
  const int blk = blockIdx.x;
  const int q = blk >> 3;
  const int nb = (blk & 7)*8 + (q & 7);   // XCD (blk&7) owns 8 consecutive nb
  const int mb = q >> 3;                  // 0..3 : the independent dependency group
  const int ksh = w & 1, cgi = w >> 1;    // K-parity, gate
  const int cgg = nb*4 + cgi;
  const int lrow = l & 15, lg = l >> 4;

  // ---- W -> registers, once ----
  bf16x8 wreg[HALF];
  #pragma unroll
  for (int j = 0; j < HALF; j++)
    wreg[j] = *(const bf16x8*)(Wpk + ((size_t)(cgg*KST_TOT + 2*j + ksh)*64 + l)*8);

  // fixed per-thread epilogue element; c stays in a register across steps
  const int erow = tid >> 4, ejj = tid & 15;
  const int R = mb*32 + erow;
  const int J = nb*16 + ejj;
  const size_t idx = (size_t)R*Hn + J;
  float creg = (LAYER == 0) ? 0.f : cst[idx];

  for (int t = 0; t < SEQn; ++t){
    // keepalive in AGPRs: unified file's accumulator half holds W permanently
    #pragma unroll
    for (int j = 0; j < HALF; j++) asm volatile("" : "+a"(wreg[j]));

    const unsigned short* A1;
    const unsigned short* A2;
    unsigned short* hout;
    if (LAYER == 0){
      A1   = hring + (size_t)t*BH;                           // h0_{t-1}
      A2   = xpp + (size_t)t*Bsz*NUMS;                       // x_t (static)
      hout = hring + (size_t)(t+1)*BH;
    } else {
      A1   = hring + (size_t)(t+1)*BH;                       // h0_t (prev kernel output)
      A2   = (t == 0) ? (hring + (size_t)SEQn*BH)
                      : (h1b + (size_t)(RING2 ? (t-1) : ((t-1)&1))*BH);
      hout = h1b + (size_t)(RING2 ? t : (t&1))*BH;
    }

    f32x4 acc2[2] = {{0.f,0.f,0.f,0.f},{0.f,0.f,0.f,0.f}};

    auto stage = [&](int ch, int kw, int lu,
                     const unsigned short* A1p, const unsigned short* A2p){
      unsigned short* dst = (LAYER == 0 && ch == NCH-1) ? sm.s.xb : sm.s.a[ch & 1];
      const int nissue = kw >> 4;                 // (32 rows * kw * 2B) / 1024B
      for (int i = w; i < nissue; i += 8){
        const int s = i*64 + l;
        const int row = s >> lu;
        const int uu  = s & ((1 << lu) - 1);
        const int ku  = uu ^ (row & 7);
        const int kg  = ch*512 + ku*8;
        const int Rr  = mb*32 + row;
        if (kg < K1){
          const unsigned short* src = A1p + (size_t)Rr*K1 + kg;
          __builtin_amdgcn_global_load_lds(
            (const __attribute__((address_space(1))) void*)src,
            (__attribute__((address_space(3))) void*)&dst[i*512], 16, 0, 0);
        } else {
          const unsigned short* src = A2p + (size_t)Rr*S2 + (kg - K1);
          if constexpr (LAYER == 1 && !RING2){
            __builtin_amdgcn_global_load_lds(   // h1 ping-pong: L3-coherent read
              (const __attribute__((address_space(1))) void*)src,
              (__attribute__((address_space(3))) void*)&dst[i*512], 16, 0, 17);
          } else {
            __builtin_amdgcn_global_load_lds(
              (const __attribute__((address_space(1))) void*)src,
              (__attribute__((address_space(3))) void*)&dst[i*512], 16, 0, 0);
          }
        }
      }
    };

    const bool pre01 = (LAYER == 1) && (t > 0);   // chunks 0,1 prefetched in barrier
    const bool preX  = (LAYER == 0) && (t > 0);   // xb chunk prefetched in barrier
    if (!pre01){
      constexpr int kw0 = (KTOT >= 512) ? 512 : KTOT;
      stage(0, kw0, (kw0 == 512) ? 6 : 4, A1, A2);
    }
    __syncthreads();

    // ---- chunk bodies with fully compile-time wreg indices (tagged lambda) ----
    auto do_chunk = [&](auto CHC){
      constexpr int ch = decltype(CHC)::value;
      if constexpr (ch < NCH){
        constexpr int kw = ((KTOT - ch*512) >= 512) ? 512 : (KTOT - ch*512);
        if constexpr (ch + 1 < NCH){
          constexpr int kwn = ((KTOT - (ch+1)*512) >= 512) ? 512 : (KTOT - (ch+1)*512);
          const bool skip = (pre01 && (ch+1) == 1) || (preX && (ch+1) == NCH-1);
          if (!skip) stage(ch+1, kwn, (kwn == 512) ? 6 : 4, A1, A2);
        }
        constexpr int UPR  = kw >> 3;
        constexpr int nksl = kw >> 6;
        const unsigned short* abase = (LAYER == 0 && ch == NCH-1) ? sm.s.xb
                                                                  : sm.s.a[ch & 1];
        #pragma unroll
        for (int ksl = 0; ksl < nksl; ksl++){
          const int klocal = ksl*2 + ksh;
          const int unit = klocal*4 + lg;
          bf16x8 af0 = *(const bf16x8*)&abase[((lrow     )*UPR + (unit ^ (lrow & 7)))*8];
          bf16x8 af1 = *(const bf16x8*)&abase[((lrow + 16)*UPR + (unit ^ (lrow & 7)))*8];
          acc2[0] = __builtin_amdgcn_mfma_f32_16x16x32_bf16(af0, wreg[ch*8 + ksl], acc2[0], 0, 0, 0);
          acc2[1] = __builtin_amdgcn_mfma_f32_16x16x32_bf16(af1, wreg[ch*8 + ksl], acc2[1], 0, 0, 0);
        }
        __syncthreads();
      }
    };
    do_chunk(IC<0>{}); do_chunk(IC<1>{}); do_chunk(IC<2>{}); do_chunk(IC<3>{});

    {   // write partials: [ksh][gate*32 + row][col]
      #pragma unroll
      for (int mi = 0; mi < 2; mi++)
        #pragma unroll
        for (int r = 0; r < 4; r++){
          const int row2 = mi*16 + lg*4 + r;
          sm.e[ksh][(cgi*32 + row2)*18 + lrow] = acc2[mi][r];
        }
    }
    __syncthreads();
    {
      float zi = sm.e[0][(0*32+erow)*18 + ejj] + sm.e[1][(0*32+erow)*18 + ejj];
      float zf = sm.e[0][(1*32+erow)*18 + ejj] + sm.e[1][(1*32+erow)*18 + ejj];
      float zo = sm.e[0][(2*32+erow)*18 + ejj] + sm.e[1][(2*32+erow)*18 + ejj];
      float zg = sm.e[0][(3*32+erow)*18 + ejj] + sm.e[1][(3*32+erow)*18 + ejj];
      zi += bias[0*Hn + J]; zf += bias[1*Hn + J];
      zo += bias[2*Hn + J]; zg += bias[3*Hn + J];
      const float gi = 1.f/(1.f + __expf(-zi));
      const float gf = 1.f/(1.f + __expf(-zf));
      const float go = 1.f/(1.f + __expf(-zo));
      const float gg = tanhf(zg);
      creg = gf * creg + gi * gg;
      const float hn = go * tanhf(creg);
      // publish h at agent scope (sc1 -> L3), packed 2x bf16 per dword
      const unsigned hu   = (unsigned)f2bf(hn);
      const unsigned mate = (unsigned)__shfl_xor((int)hu, 1);
      if ((l & 1) == 0){
        const unsigned pk = hu | (mate << 16);
        __hip_atomic_store((unsigned*)(hout + idx), pk,
                           __ATOMIC_RELAXED, __HIP_MEMORY_SCOPE_AGENT);
      }
      if (t == SEQn-1){
        cst[idx] = creg;                 // layer handoff / final output (kernel boundary)
        if (LAYER == 1) hf_out[idx] = hn;
      }
    }

    if (t + 1 < SEQn){
      // ---- per-mb (64-arrival) barrier with in-barrier prefetch ----
      __syncthreads();                   // drains vmcnt: h-publishes at L3; sm free
      if (tid == 0)
        __hip_atomic_fetch_add(&bar[t*4 + mb], 1u,
                               __ATOMIC_RELAXED, __HIP_MEMORY_SCOPE_AGENT);
      if constexpr (LAYER == 1){
        // next step's region1 = h0 ring slot t+2: written by the PREVIOUS kernel ->
        // stable; chunks 0,1 are entirely kg < K1, so A2 is never dereferenced.
        const unsigned short* A1n = hring + (size_t)(t+2)*BH;
        stage(0, 512, 6, A1n, A1n);
        stage(1, 512, 6, A1n, A1n);
      } else {
        // next step's region2 = xp_{t+1}: static input -> prefetch into xb.
        stage(NCH-1, 128, 4, A1, xpp + (size_t)(t+1)*Bsz*NUMS);
      }
      if (tid == 0){
        while (__hip_atomic_load(&bar[t*4 + mb], __ATOMIC_RELAXED,
                                 __HIP_MEMORY_SCOPE_AGENT) < 64u)
          __builtin_amdgcn_s_sleep(1);
      }
      __syncthreads();                   // exit: also drains the prefetch issued above
    }
  }
}

// ---- final FC + copy h,c to d_out ----
__global__ __launch_bounds__(256)
void fc_out_kernel(const float* __restrict__ hf, const float* __restrict__ cst,
                   const float* __restrict__ fcw, const float* __restrict__ fcb,
                   float* __restrict__ dout){
  __shared__ float hrow[Hn];
  const int b = blockIdx.x, tid = threadIdx.x;
  for (int i = tid; i < Hn; i += 256) hrow[i] = hf[(size_t)b*Hn + i];
  __syncthreads();
  if (tid < PRED){
    float a = fcb[tid];
    for (int k = 0; k < Hn; k++) a += hrow[k] * fcw[(size_t)k*PRED + tid];
    dout[(size_t)b*PRED + tid] = tanhf(a);
  }
  for (int i = tid; i < Hn; i += 256){
    dout[Bsz*PRED + (size_t)b*Hn + i] = hf[(size_t)b*Hn + i];
    dout[Bsz*PRED + (size_t)Bsz*Hn + (size_t)b*Hn + i] = cst[(size_t)b*Hn + i];
  }
}

extern "C" void kernel_launch(void* const* d_in, const int* in_sizes, int n_in,
                              void* d_out, int out_size, void* d_ws, size_t ws_size,
                              hipStream_t stream){
  const float* x   = (const float*)d_in[0];
  const float* W0  = (const float*)d_in[1];
  const float* b0  = (const float*)d_in[2];
  const float* W1  = (const float*)d_in[3];
  const float* b1  = (const float*)d_in[4];
  const float* fcw = (const float*)d_in[5];
  const float* fcb = (const float*)d_in[6];
  float* dout = (float*)d_out;

  char* p = (char*)d_ws;
  auto alloc = [&](size_t bytes)->void*{
    void* r = (void*)p; p += (bytes + 255) & ~(size_t)255; return r;
  };
  // base footprint ~103.5 MB (proven); +67 MB h1 ring only if workspace allows
  unsigned short* xp   = (unsigned short*)alloc((size_t)SEQn*Bsz*NUMS*2);      // 8.4 MB
  unsigned short* Wpk0 = (unsigned short*)alloc((size_t)256*36*64*8*2);        // 9.4 MB
  unsigned short* Wpk1 = (unsigned short*)alloc((size_t)256*64*64*8*2);        // 16.8 MB
  unsigned short* H0   = (unsigned short*)alloc((size_t)(SEQn+1)*BH*2);        // 67.4 MB
  float* cst = (float*)alloc((size_t)BH*4);                                    // 0.5 MB
  float* hf  = (float*)alloc((size_t)BH*4);                                    // 0.5 MB
  unsigned* bars = (unsigned*)alloc((size_t)2048*sizeof(unsigned));            // 8 KB

  const bool big = ws_size >= (size_t)176*1024*1024;   // room for write-once h1 ring?
  unsigned short* h1b;
  if (big) h1b = (unsigned short*)alloc((size_t)SEQn*BH*2);                    // 67.1 MB
  else     h1b = (unsigned short*)alloc((size_t)2*BH*2);                       // 0.5 MB

  pack_x_kernel<<<dim3(SEQn/64, NUMS/64, Bsz), dim3(256), 0, stream>>>(x, xp);
  // W0 packed K order: [h rows 128..1151 -> kst 0..31][x rows 0..127 -> kst 32..35]
  pack_w_kernel<<<dim3((256*32*64 + 255)/256), dim3(256), 0, stream>>>(W0, Wpk0, 32, 128, 36, 0);
  pack_w_kernel<<<dim3((256*4*64  + 255)/256), dim3(256), 0, stream>>>(W0, Wpk0,  4,   0, 36, 32);
  // W1: rows 0..1023 = h0-part, 1024..2047 = h1-part (natural order)
  pack_w_kernel<<<dim3((256*64*64 + 255)/256), dim3(256), 0, stream>>>(W1, Wpk1, 64, 0, 64, 0);
  zero_kernel<<<dim3((Bsz*Hn + 255)/256), dim3(256), 0, stream>>>(H0, cst, bars);

  // layer 0: ONE persistent launch, 256 barriered steps (K = [h 1024 | x 128])
  persist_kernel<1024, NUMS, 1152, 0, false><<<dim3(GN), dim3(512), 0, stream>>>(
      xp, H0, nullptr, Wpk0, b0, cst, nullptr, bars);

  // layer 1: ONE persistent launch (K = [h0 1024 | h1 1024])
  if (big){
    persist_kernel<1024, Hn, 2048, 1, true><<<dim3(GN), dim3(512), 0, stream>>>(
        nullptr, H0, h1b, Wpk1, b1, cst, hf, bars + 1024);
  } else {
    persist_kernel<1024, Hn, 2048, 1, false><<<dim3(GN), dim3(512), 0, stream>>>(
        nullptr, H0, h1b, Wpk1, b1, cst, hf, bars + 1024);
  }

  fc_out_kernel<<<dim3(Bsz), dim3(256), 0, stream>>>(hf, cst, fcw, fcb, dout);
}

// Round 10
// 3595.077 us; speedup vs baseline: 1.3004x; 1.3004x over previous
//
#include <hip/hip_runtime.h>
#include <stdint.h>

#define Bsz  128
#define NUMS 128
#define SEQn 256
#define Hn   1024
#define PRED 96
#define G4H  4096
#define GN   256            // persistent grid: 256 blocks = 64 nb x 4 mb (1 per CU)
#define BH   ((size_t)Bsz*Hn)

typedef __attribute__((ext_vector_type(8))) short bf16x8;
typedef __attribute__((ext_vector_type(4))) float f32x4;

template<int N> struct IC { static constexpr int value = N; };

__device__ __forceinline__ unsigned short f2bf(float x){
  union { float f; unsigned u; } v; v.f = x;
  return (unsigned short)((v.u + 0x7FFFu + ((v.u >> 16) & 1u)) >> 16);
}

// ---- pack x: [B][NUMS][SEQ] f32 -> xp [SEQ][B][NUMS] bf16 (LDS transpose) ----
__global__ void pack_x_kernel(const float* __restrict__ x, unsigned short* __restrict__ xp){
  __shared__ float tile[64][65];
  const int t0 = blockIdx.x * 64, n0 = blockIdx.y * 64, b = blockIdx.z;
  const int tid = threadIdx.x;
  const int c = tid & 63, r = tid >> 6;
  #pragma unroll
  for (int i = 0; i < 16; i++){
    int n = r + i*4;
    tile[n][c] = x[((size_t)b*NUMS + n0 + n)*SEQn + t0 + c];
  }
  __syncthreads();
  #pragma unroll
  for (int i = 0; i < 16; i++){
    int t = r + i*4;
    xp[((size_t)(t0+t)*Bsz + b)*NUMS + n0 + c] = f2bf(tile[c][t]);
  }
}

// ---- pack W rows into MFMA B-frag order: Wpk[cgg][kof+kst][lane][8] ----
__global__ void pack_w_kernel(const float* __restrict__ W, unsigned short* __restrict__ Wpk,
                              int KST, int row_off, int kstride, int kof){
  const int u = blockIdx.x * blockDim.x + threadIdx.x;
  if (u >= 256*KST*64) return;
  const int lane = u & 63;
  const int kst  = (u >> 6) % KST;
  const int cgg  = (u >> 6) / KST;
  const int nb = cgg >> 2, gate = cgg & 3;
  const int col = gate*Hn + nb*16 + (lane & 15);
  const int kbase = row_off + kst*32 + (lane >> 4)*8;
  unsigned short tmp[8];
  #pragma unroll
  for (int e = 0; e < 8; e++) tmp[e] = f2bf(W[(size_t)(kbase+e)*G4H + col]);
  ((ulonglong2*)Wpk)[(size_t)(cgg*kstride + kof + kst)*64 + lane] = *(const ulonglong2*)tmp;
}

__global__ void zero_kernel(unsigned short* __restrict__ h0, float* __restrict__ c,
                            unsigned* __restrict__ bars){
  int i = blockIdx.x*256 + threadIdx.x;
  if (i < Bsz*Hn){ h0[i] = 0; c[i] = 0.0f; }
  if (i < 1024) bars[i] = 0u;
}

// ---- persistent LSTM layer: round-6 structure + front-loaded chunk schedule ----
// grid 256 = 64 nb x 4 mb (1/CU), 512 thr = 8 waves = 4 gates x 2 K-parities.
// ONE change vs round 6 (3528us proven): each chunk gets its OWN LDS buffer and all
// of a step's loads are issued up front; already-resident chunks compute first, then
// ONE __syncthreads covers the in-flight rest. Syncs/step: 8 -> 4.
//   LAYER=0: [ch0,ch1]=h0_{t-1} (post-barrier issue), xb=x_t (in-barrier prefetch).
//            Order: issue ch0,ch1; comp(x); sync; comp(ch0,ch1).
//   LAYER=1: [ch0,ch1]=h0_t (in-barrier prefetch, slot t+2 is prev-kernel-stable),
//            [ch2,ch3]=h1_{t-1} (RING2 ring or aux=17 ping-pong).
//            Order: issue ch2,ch3; comp(ch0,ch1); sync; comp(ch2,ch3).
// Barrier: single 256-arrival counter bar[t] (per-mb 64-arrival REGRESSED, r7/r9).
// c lives in ONE register per thread across all 256 steps. W keepalive "+v" as r6.
template<int K1, int S2, int KTOT, int LAYER, bool RING2>
__global__ __launch_bounds__(512, 2)
void persist_kernel(const unsigned short* __restrict__ xpp,
                    unsigned short* __restrict__ hring,
                    unsigned short* __restrict__ h1b,
                    const unsigned short* __restrict__ Wpk,
                    const float* __restrict__ bias,
                    float* __restrict__ cst,
                    float* __restrict__ hf_out,
                    unsigned* __restrict__ bar)
{
  constexpr int KST_TOT = KTOT/32;
  constexpr int HALF = KST_TOT/2;
  constexpr int NCH = (KTOT + 511)/512;                 // 3 (L0: 2 full + x) or 4 (L1)
  constexpr int NBUF = (LAYER == 0) ? 2 : 4;
  __shared__ unsigned short sa[NBUF][32*512];           // 32KB per full chunk
  __shared__ unsigned short sxb[(LAYER == 0) ? 32*128 : 64];  // L0 x-chunk (8KB)
  __shared__ float se[2][4*32*18];                      // epilogue partials (18.4KB)

  const int tid = threadIdx.x;
  const int w = tid >> 6, l = tid & 63;
  const int blk = blockIdx.x;
  const int q = blk >> 3;
  const int nb = (blk & 7)*8 + (q & 7);   // XCD (blk&7) owns 8 consecutive nb
  const int mb = q >> 3;                  // 0..3, 32 rows each
  const int ksh = w & 1, cgi = w >> 1;    // K-parity, gate
  const int cgg = nb*4 + cgi;
  const int lrow = l & 15, lg = l >> 4;

  // ---- W -> registers, once ----
  bf16x8 wreg[HALF];
  #pragma unroll
  for (int j = 0; j < HALF; j++)
    wreg[j] = *(const bf16x8*)(Wpk + ((size_t)(cgg*KST_TOT + 2*j + ksh)*64 + l)*8);

  // fixed per-thread epilogue element; c stays in a register across steps
  const int erow = tid >> 4, ejj = tid & 15;
  const int R = mb*32 + erow;
  const int J = nb*16 + ejj;
  const size_t idx = (size_t)R*Hn + J;
  float creg = (LAYER == 0) ? 0.f : cst[idx];

  for (int t = 0; t < SEQn; ++t){
    // keepalive: keep W materialized (round-6 proven form)
    #pragma unroll
    for (int j = 0; j < HALF; j++) asm volatile("" : "+v"(wreg[j]));

    const unsigned short* A1;
    const unsigned short* A2;
    unsigned short* hout;
    if (LAYER == 0){
      A1   = hring + (size_t)t*BH;                           // h0_{t-1}
      A2   = xpp + (size_t)t*Bsz*NUMS;                       // x_t (static)
      hout = hring + (size_t)(t+1)*BH;
    } else {
      A1   = hring + (size_t)(t+1)*BH;                       // h0_t (prev kernel output)
      A2   = (t == 0) ? (hring + (size_t)SEQn*BH)
                      : (h1b + (size_t)(RING2 ? (t-1) : ((t-1)&1))*BH);
      hout = h1b + (size_t)(RING2 ? t : (t&1))*BH;
    }

    f32x4 acc2[2] = {{0.f,0.f,0.f,0.f},{0.f,0.f,0.f,0.f}};

    auto stage = [&](int ch, int kw, int lu,
                     const unsigned short* A1p, const unsigned short* A2p){
      unsigned short* dst = (LAYER == 0 && ch == NCH-1) ? sxb : sa[ch];
      const int nissue = kw >> 4;                 // (32 rows * kw * 2B) / 1024B
      for (int i = w; i < nissue; i += 8){
        const int s = i*64 + l;
        const int row = s >> lu;
        const int uu  = s & ((1 << lu) - 1);
        const int ku  = uu ^ (row & 7);
        const int kg  = ch*512 + ku*8;
        const int Rr  = mb*32 + row;
        if (kg < K1){
          const unsigned short* src = A1p + (size_t)Rr*K1 + kg;
          __builtin_amdgcn_global_load_lds(
            (const __attribute__((address_space(1))) void*)src,
            (__attribute__((address_space(3))) void*)&dst[i*512], 16, 0, 0);
        } else {
          const unsigned short* src = A2p + (size_t)Rr*S2 + (kg - K1);
          if constexpr (LAYER == 1 && !RING2){
            __builtin_amdgcn_global_load_lds(   // h1 ping-pong: L3-coherent read
              (const __attribute__((address_space(1))) void*)src,
              (__attribute__((address_space(3))) void*)&dst[i*512], 16, 0, 17);
          } else {
            __builtin_amdgcn_global_load_lds(
              (const __attribute__((address_space(1))) void*)src,
              (__attribute__((address_space(3))) void*)&dst[i*512], 16, 0, 0);
          }
        }
      }
    };

    // compile-time chunk compute (wreg indices all literal)
    auto comp = [&](auto CHC){
      constexpr int ch = decltype(CHC)::value;
      if constexpr (ch < NCH){
        constexpr bool isx = (LAYER == 0 && ch == NCH-1);
        constexpr int kw   = isx ? 128 : 512;
        constexpr int UPR  = kw >> 3;
        constexpr int nksl = kw >> 6;
        const unsigned short* abase = isx ? sxb : sa[ch];
        #pragma unroll
        for (int ksl = 0; ksl < nksl; ksl++){
          const int klocal = ksl*2 + ksh;
          const int unit = klocal*4 + lg;
          bf16x8 af0 = *(const bf16x8*)&abase[((lrow     )*UPR + (unit ^ (lrow & 7)))*8];
          bf16x8 af1 = *(const bf16x8*)&abase[((lrow + 16)*UPR + (unit ^ (lrow & 7)))*8];
          acc2[0] = __builtin_amdgcn_mfma_f32_16x16x32_bf16(af0, wreg[ch*8 + ksl], acc2[0], 0, 0, 0);
          acc2[1] = __builtin_amdgcn_mfma_f32_16x16x32_bf16(af1, wreg[ch*8 + ksl], acc2[1], 0, 0, 0);
        }
      }
    };

    if (t == 0){
      // prologue: everything cold — issue all, one sync, compute all
      stage(0, 512, 6, A1, A2); stage(1, 512, 6, A1, A2);
      if constexpr (LAYER == 1){ stage(2, 512, 6, A1, A2); stage(3, 512, 6, A1, A2); }
      else                       stage(2, 128, 4, A1, A2);
      __syncthreads();
      comp(IC<0>{}); comp(IC<1>{}); comp(IC<2>{}); comp(IC<3>{});
    } else if constexpr (LAYER == 1){
      // ch0,ch1 (h0) resident from in-barrier prefetch (drained at barrier exit)
      stage(2, 512, 6, A1, A2); stage(3, 512, 6, A1, A2);   // h1 reads fly...
      comp(IC<0>{}); comp(IC<1>{});                         // ...under h0 compute
      __syncthreads();                                      // waits ch2,ch3
      comp(IC<2>{}); comp(IC<3>{});
    } else {
      // xb resident from in-barrier prefetch
      stage(0, 512, 6, A1, A2); stage(1, 512, 6, A1, A2);   // h reads fly...
      comp(IC<2>{});                                        // ...under x compute
      __syncthreads();                                      // waits ch0,ch1
      comp(IC<0>{}); comp(IC<1>{});
    }

    {   // write partials: [ksh][gate*32 + row][col]
      #pragma unroll
      for (int mi = 0; mi < 2; mi++)
        #pragma unroll
        for (int r = 0; r < 4; r++){
          const int row2 = mi*16 + lg*4 + r;
          se[ksh][(cgi*32 + row2)*18 + lrow] = acc2[mi][r];
        }
    }
    __syncthreads();
    {
      float zi = se[0][(0*32+erow)*18 + ejj] + se[1][(0*32+erow)*18 + ejj];
      float zf = se[0][(1*32+erow)*18 + ejj] + se[1][(1*32+erow)*18 + ejj];
      float zo = se[0][(2*32+erow)*18 + ejj] + se[1][(2*32+erow)*18 + ejj];
      float zg = se[0][(3*32+erow)*18 + ejj] + se[1][(3*32+erow)*18 + ejj];
      zi += bias[0*Hn + J]; zf += bias[1*Hn + J];
      zo += bias[2*Hn + J]; zg += bias[3*Hn + J];
      const float gi = 1.f/(1.f + __expf(-zi));
      const float gf = 1.f/(1.f + __expf(-zf));
      const float go = 1.f/(1.f + __expf(-zo));
      const float gg = tanhf(zg);
      creg = gf * creg + gi * gg;
      const float hn = go * tanhf(creg);
      // publish h at agent scope (sc1 -> L3), packed 2x bf16 per dword
      const unsigned hu   = (unsigned)f2bf(hn);
      const unsigned mate = (unsigned)__shfl_xor((int)hu, 1);
      if ((l & 1) == 0){
        const unsigned pk = hu | (mate << 16);
        __hip_atomic_store((unsigned*)(hout + idx), pk,
                           __ATOMIC_RELAXED, __HIP_MEMORY_SCOPE_AGENT);
      }
      if (t == SEQn-1){
        cst[idx] = creg;                 // layer handoff / final output (kernel boundary)
        if (LAYER == 1) hf_out[idx] = hn;
      }
    }

    if (t + 1 < SEQn){
      // ---- 256-arrival grid barrier with in-barrier prefetch (round-6 form) ----
      __syncthreads();                   // drains vmcnt: h-publishes at L3; LDS free
      if (tid == 0)
        __hip_atomic_fetch_add(&bar[t], 1u, __ATOMIC_RELAXED, __HIP_MEMORY_SCOPE_AGENT);
      if constexpr (LAYER == 1){
        // next step's h0 = ring slot t+2: written by the PREVIOUS kernel -> stable
        const unsigned short* A1n = hring + (size_t)(t+2)*BH;
        stage(0, 512, 6, A1n, A1n);
        stage(1, 512, 6, A1n, A1n);
      } else {
        stage(NCH-1, 128, 4, A1, xpp + (size_t)(t+1)*Bsz*NUMS);   // x static
      }
      if (tid == 0){
        while (__hip_atomic_load(&bar[t], __ATOMIC_RELAXED, __HIP_MEMORY_SCOPE_AGENT) < GN)
          __builtin_amdgcn_s_sleep(1);
      }
      __syncthreads();                   // exit: also drains the prefetch issued above
    }
  }
}

// ---- final FC + copy h,c to d_out ----
__global__ __launch_bounds__(256)
void fc_out_kernel(const float* __restrict__ hf, const float* __restrict__ cst,
                   const float* __restrict__ fcw, const float* __restrict__ fcb,
                   float* __restrict__ dout){
  __shared__ float hrow[Hn];
  const int b = blockIdx.x, tid = threadIdx.x;
  for (int i = tid; i < Hn; i += 256) hrow[i] = hf[(size_t)b*Hn + i];
  __syncthreads();
  if (tid < PRED){
    float a = fcb[tid];
    for (int k = 0; k < Hn; k++) a += hrow[k] * fcw[(size_t)k*PRED + tid];
    dout[(size_t)b*PRED + tid] = tanhf(a);
  }
  for (int i = tid; i < Hn; i += 256){
    dout[Bsz*PRED + (size_t)b*Hn + i] = hf[(size_t)b*Hn + i];
    dout[Bsz*PRED + (size_t)Bsz*Hn + (size_t)b*Hn + i] = cst[(size_t)b*Hn + i];
  }
}

extern "C" void kernel_launch(void* const* d_in, const int* in_sizes, int n_in,
                              void* d_out, int out_size, void* d_ws, size_t ws_size,
                              hipStream_t stream){
  const float* x   = (const float*)d_in[0];
  const float* W0  = (const float*)d_in[1];
  const float* b0  = (const float*)d_in[2];
  const float* W1  = (const float*)d_in[3];
  const float* b1  = (const float*)d_in[4];
  const float* fcw = (const float*)d_in[5];
  const float* fcb = (const float*)d_in[6];
  float* dout = (float*)d_out;

  char* p = (char*)d_ws;
  auto alloc = [&](size_t bytes)->void*{
    void* r = (void*)p; p += (bytes + 255) & ~(size_t)255; return r;
  };
  // base footprint ~103.5 MB (proven); +67 MB h1 ring only if workspace allows
  unsigned short* xp   = (unsigned short*)alloc((size_t)SEQn*Bsz*NUMS*2);      // 8.4 MB
  unsigned short* Wpk0 = (unsigned short*)alloc((size_t)256*36*64*8*2);        // 9.4 MB
  unsigned short* Wpk1 = (unsigned short*)alloc((size_t)256*64*64*8*2);        // 16.8 MB
  unsigned short* H0   = (unsigned short*)alloc((size_t)(SEQn+1)*BH*2);        // 67.4 MB
  float* cst = (float*)alloc((size_t)BH*4);                                    // 0.5 MB
  float* hf  = (float*)alloc((size_t)BH*4);                                    // 0.5 MB
  unsigned* bars = (unsigned*)alloc((size_t)1024*sizeof(unsigned));            // 4 KB

  const bool big = ws_size >= (size_t)176*1024*1024;   // room for write-once h1 ring?
  unsigned short* h1b;
  if (big) h1b = (unsigned short*)alloc((size_t)SEQn*BH*2);                    // 67.1 MB
  else     h1b = (unsigned short*)alloc((size_t)2*BH*2);                       // 0.5 MB

  pack_x_kernel<<<dim3(SEQn/64, NUMS/64, Bsz), dim3(256), 0, stream>>>(x, xp);
  // W0 packed K order: [h rows 128..1151 -> kst 0..31][x rows 0..127 -> kst 32..35]
  pack_w_kernel<<<dim3((256*32*64 + 255)/256), dim3(256), 0, stream>>>(W0, Wpk0, 32, 128, 36, 0);
  pack_w_kernel<<<dim3((256*4*64  + 255)/256), dim3(256), 0, stream>>>(W0, Wpk0,  4,   0, 36, 32);
  // W1: rows 0..1023 = h0-part, 1024..2047 = h1-part (natural order)
  pack_w_kernel<<<dim3((256*64*64 + 255)/256), dim3(256), 0, stream>>>(W1, Wpk1, 64, 0, 64, 0);
  zero_kernel<<<dim3((Bsz*Hn + 255)/256), dim3(256), 0, stream>>>(H0, cst, bars);

  // layer 0: ONE persistent launch, 256 barriered steps (K = [h 1024 | x 128])
  persist_kernel<1024, NUMS, 1152, 0, false><<<dim3(GN), dim3(512), 0, stream>>>(
      xp, H0, nullptr, Wpk0, b0, cst, nullptr, bars);

  // layer 1: ONE persistent launch (K = [h0 1024 | h1 1024])
  if (big){
    persist_kernel<1024, Hn, 2048, 1, true><<<dim3(GN), dim3(512), 0, stream>>>(
        nullptr, H0, h1b, Wpk1, b1, cst, hf, bars + 512);
  } else {
    persist_kernel<1024, Hn, 2048, 1, false><<<dim3(GN), dim3(512), 0, stream>>>(
        nullptr, H0, h1b, Wpk1, b1, cst, hf, bars + 512);
  }

  fc_out_kernel<<<dim3(Bsz), dim3(256), 0, stream>>>(hf, cst, fcw, fcb, dout);
}

// Round 11
// 3423.704 us; speedup vs baseline: 1.3655x; 1.0501x over previous
//
#include <hip/hip_runtime.h>
#include <stdint.h>

#define Bsz  128
#define NUMS 128
#define SEQn 256
#define Hn   1024
#define PRED 96
#define G4H  4096
#define GN   256            // persistent grid: 256 blocks = 64 nb x 4 mb (1 per CU)
#define BH   ((size_t)Bsz*Hn)

typedef __attribute__((ext_vector_type(8))) short bf16x8;
typedef __attribute__((ext_vector_type(4))) float f32x4;

template<int N> struct IC { static constexpr int value = N; };

__device__ __forceinline__ unsigned short f2bf(float x){
  union { float f; unsigned u; } v; v.f = x;
  return (unsigned short)((v.u + 0x7FFFu + ((v.u >> 16) & 1u)) >> 16);
}

// ---- pack x: [B][NUMS][SEQ] f32 -> xp [SEQ][B][NUMS] bf16 (LDS transpose) ----
__global__ void pack_x_kernel(const float* __restrict__ x, unsigned short* __restrict__ xp){
  __shared__ float tile[64][65];
  const int t0 = blockIdx.x * 64, n0 = blockIdx.y * 64, b = blockIdx.z;
  const int tid = threadIdx.x;
  const int c = tid & 63, r = tid >> 6;
  #pragma unroll
  for (int i = 0; i < 16; i++){
    int n = r + i*4;
    tile[n][c] = x[((size_t)b*NUMS + n0 + n)*SEQn + t0 + c];
  }
  __syncthreads();
  #pragma unroll
  for (int i = 0; i < 16; i++){
    int t = r + i*4;
    xp[((size_t)(t0+t)*Bsz + b)*NUMS + n0 + c] = f2bf(tile[c][t]);
  }
}

// ---- pack W rows into MFMA B-frag order: Wpk[cgg][kof+kst][lane][8] ----
__global__ void pack_w_kernel(const float* __restrict__ W, unsigned short* __restrict__ Wpk,
                              int KST, int row_off, int kstride, int kof){
  const int u = blockIdx.x * blockDim.x + threadIdx.x;
  if (u >= 256*KST*64) return;
  const int lane = u & 63;
  const int kst  = (u >> 6) % KST;
  const int cgg  = (u >> 6) / KST;
  const int nb = cgg >> 2, gate = cgg & 3;
  const int col = gate*Hn + nb*16 + (lane & 15);
  const int kbase = row_off + kst*32 + (lane >> 4)*8;
  unsigned short tmp[8];
  #pragma unroll
  for (int e = 0; e < 8; e++) tmp[e] = f2bf(W[(size_t)(kbase+e)*G4H + col]);
  ((ulonglong2*)Wpk)[(size_t)(cgg*kstride + kof + kst)*64 + lane] = *(const ulonglong2*)tmp;
}

__global__ void zero_kernel(unsigned short* __restrict__ h0, float* __restrict__ c,
                            unsigned* __restrict__ bars){
  int i = blockIdx.x*256 + threadIdx.x;
  if (i < Bsz*Hn){ h0[i] = 0; c[i] = 0.0f; }
  if (i < 2048) bars[i] = 0u;
}

// ---- persistent LSTM layer: round-10 structure + HIERARCHICAL padded barrier ----
// grid 256 = 64 nb x 4 mb (1/CU), 512 thr = 8 waves = 4 gates x 2 K-parities.
// ONE change vs round 10 (3595us, L1 7.6us/step): barrier arrival was 256 fetch_adds
// on ONE L3 line -> serialized RMWs ~4us/step (also explains r7/r9 regression: the 4
// per-mb counters shared a 64B line). Now: 32 group counters (8 blocks each), EACH ON
// ITS OWN 64B LINE, monotonic; 8th group arriver adds to padded root; 32nd root
// arriver stores padded release word rel = t+1; all blocks spin on rel.
// bar layout (u32 idx): grp g at [g*16] (g=0..31), root at [512], rel at [528].
template<int K1, int S2, int KTOT, int LAYER, bool RING2>
__global__ __launch_bounds__(512, 2)
void persist_kernel(const unsigned short* __restrict__ xpp,
                    unsigned short* __restrict__ hring,
                    unsigned short* __restrict__ h1b,
                    const unsigned short* __restrict__ Wpk,
                    const float* __restrict__ bias,
                    float* __restrict__ cst,
                    float* __restrict__ hf_out,
                    unsigned* __restrict__ bar)
{
  constexpr int KST_TOT = KTOT/32;
  constexpr int HALF = KST_TOT/2;
  constexpr int NCH = (KTOT + 511)/512;                 // 3 (L0: 2 full + x) or 4 (L1)
  constexpr int NBUF = (LAYER == 0) ? 2 : 4;
  __shared__ unsigned short sa[NBUF][32*512];           // 32KB per full chunk
  __shared__ unsigned short sxb[(LAYER == 0) ? 32*128 : 64];  // L0 x-chunk (8KB)
  __shared__ float se[2][4*32*18];                      // epilogue partials (18.4KB)

  const int tid = threadIdx.x;
  const int w = tid >> 6, l = tid & 63;
  const int blk = blockIdx.x;
  const int q = blk >> 3;
  const int nb = (blk & 7)*8 + (q & 7);   // XCD (blk&7) owns 8 consecutive nb
  const int mb = q >> 3;                  // 0..3, 32 rows each
  const int ksh = w & 1, cgi = w >> 1;    // K-parity, gate
  const int cgg = nb*4 + cgi;
  const int lrow = l & 15, lg = l >> 4;
  const int bgrp = blk >> 3;              // barrier group (32 groups of 8)

  // ---- W -> registers, once ----
  bf16x8 wreg[HALF];
  #pragma unroll
  for (int j = 0; j < HALF; j++)
    wreg[j] = *(const bf16x8*)(Wpk + ((size_t)(cgg*KST_TOT + 2*j + ksh)*64 + l)*8);

  // fixed per-thread epilogue element; c stays in a register across steps
  const int erow = tid >> 4, ejj = tid & 15;
  const int R = mb*32 + erow;
  const int J = nb*16 + ejj;
  const size_t idx = (size_t)R*Hn + J;
  float creg = (LAYER == 0) ? 0.f : cst[idx];

  for (int t = 0; t < SEQn; ++t){
    // keepalive: keep W materialized (round-6 proven form)
    #pragma unroll
    for (int j = 0; j < HALF; j++) asm volatile("" : "+v"(wreg[j]));

    const unsigned short* A1;
    const unsigned short* A2;
    unsigned short* hout;
    if (LAYER == 0){
      A1   = hring + (size_t)t*BH;                           // h0_{t-1}
      A2   = xpp + (size_t)t*Bsz*NUMS;                       // x_t (static)
      hout = hring + (size_t)(t+1)*BH;
    } else {
      A1   = hring + (size_t)(t+1)*BH;                       // h0_t (prev kernel output)
      A2   = (t == 0) ? (hring + (size_t)SEQn*BH)
                      : (h1b + (size_t)(RING2 ? (t-1) : ((t-1)&1))*BH);
      hout = h1b + (size_t)(RING2 ? t : (t&1))*BH;
    }

    f32x4 acc2[2] = {{0.f,0.f,0.f,0.f},{0.f,0.f,0.f,0.f}};

    auto stage = [&](int ch, int kw, int lu,
                     const unsigned short* A1p, const unsigned short* A2p){
      unsigned short* dst = (LAYER == 0 && ch == NCH-1) ? sxb : sa[ch];
      const int nissue = kw >> 4;                 // (32 rows * kw * 2B) / 1024B
      for (int i = w; i < nissue; i += 8){
        const int s = i*64 + l;
        const int row = s >> lu;
        const int uu  = s & ((1 << lu) - 1);
        const int ku  = uu ^ (row & 7);
        const int kg  = ch*512 + ku*8;
        const int Rr  = mb*32 + row;
        if (kg < K1){
          const unsigned short* src = A1p + (size_t)Rr*K1 + kg;
          __builtin_amdgcn_global_load_lds(
            (const __attribute__((address_space(1))) void*)src,
            (__attribute__((address_space(3))) void*)&dst[i*512], 16, 0, 0);
        } else {
          const unsigned short* src = A2p + (size_t)Rr*S2 + (kg - K1);
          if constexpr (LAYER == 1 && !RING2){
            __builtin_amdgcn_global_load_lds(   // h1 ping-pong: L3-coherent read
              (const __attribute__((address_space(1))) void*)src,
              (__attribute__((address_space(3))) void*)&dst[i*512], 16, 0, 17);
          } else {
            __builtin_amdgcn_global_load_lds(
              (const __attribute__((address_space(1))) void*)src,
              (__attribute__((address_space(3))) void*)&dst[i*512], 16, 0, 0);
          }
        }
      }
    };

    // compile-time chunk compute (wreg indices all literal)
    auto comp = [&](auto CHC){
      constexpr int ch = decltype(CHC)::value;
      if constexpr (ch < NCH){
        constexpr bool isx = (LAYER == 0 && ch == NCH-1);
        constexpr int kw   = isx ? 128 : 512;
        constexpr int UPR  = kw >> 3;
        constexpr int nksl = kw >> 6;
        const unsigned short* abase = isx ? sxb : sa[ch];
        #pragma unroll
        for (int ksl = 0; ksl < nksl; ksl++){
          const int klocal = ksl*2 + ksh;
          const int unit = klocal*4 + lg;
          bf16x8 af0 = *(const bf16x8*)&abase[((lrow     )*UPR + (unit ^ (lrow & 7)))*8];
          bf16x8 af1 = *(const bf16x8*)&abase[((lrow + 16)*UPR + (unit ^ (lrow & 7)))*8];
          acc2[0] = __builtin_amdgcn_mfma_f32_16x16x32_bf16(af0, wreg[ch*8 + ksl], acc2[0], 0, 0, 0);
          acc2[1] = __builtin_amdgcn_mfma_f32_16x16x32_bf16(af1, wreg[ch*8 + ksl], acc2[1], 0, 0, 0);
        }
      }
    };

    if (t == 0){
      // prologue: everything cold — issue all, one sync, compute all
      stage(0, 512, 6, A1, A2); stage(1, 512, 6, A1, A2);
      if constexpr (LAYER == 1){ stage(2, 512, 6, A1, A2); stage(3, 512, 6, A1, A2); }
      else                       stage(2, 128, 4, A1, A2);
      __syncthreads();
      comp(IC<0>{}); comp(IC<1>{}); comp(IC<2>{}); comp(IC<3>{});
    } else if constexpr (LAYER == 1){
      // ch0,ch1 (h0) resident from in-barrier prefetch (drained at barrier exit)
      stage(2, 512, 6, A1, A2); stage(3, 512, 6, A1, A2);   // h1 reads fly...
      comp(IC<0>{}); comp(IC<1>{});                         // ...under h0 compute
      __syncthreads();                                      // waits ch2,ch3
      comp(IC<2>{}); comp(IC<3>{});
    } else {
      // xb resident from in-barrier prefetch
      stage(0, 512, 6, A1, A2); stage(1, 512, 6, A1, A2);   // h reads fly...
      comp(IC<2>{});                                        // ...under x compute
      __syncthreads();                                      // waits ch0,ch1
      comp(IC<0>{}); comp(IC<1>{});
    }

    {   // write partials: [ksh][gate*32 + row][col]
      #pragma unroll
      for (int mi = 0; mi < 2; mi++)
        #pragma unroll
        for (int r = 0; r < 4; r++){
          const int row2 = mi*16 + lg*4 + r;
          se[ksh][(cgi*32 + row2)*18 + lrow] = acc2[mi][r];
        }
    }
    __syncthreads();
    {
      float zi = se[0][(0*32+erow)*18 + ejj] + se[1][(0*32+erow)*18 + ejj];
      float zf = se[0][(1*32+erow)*18 + ejj] + se[1][(1*32+erow)*18 + ejj];
      float zo = se[0][(2*32+erow)*18 + ejj] + se[1][(2*32+erow)*18 + ejj];
      float zg = se[0][(3*32+erow)*18 + ejj] + se[1][(3*32+erow)*18 + ejj];
      zi += bias[0*Hn + J]; zf += bias[1*Hn + J];
      zo += bias[2*Hn + J]; zg += bias[3*Hn + J];
      const float gi = 1.f/(1.f + __expf(-zi));
      const float gf = 1.f/(1.f + __expf(-zf));
      const float go = 1.f/(1.f + __expf(-zo));
      const float gg = tanhf(zg);
      creg = gf * creg + gi * gg;
      const float hn = go * tanhf(creg);
      // publish h at agent scope (sc1 -> L3), packed 2x bf16 per dword
      const unsigned hu   = (unsigned)f2bf(hn);
      const unsigned mate = (unsigned)__shfl_xor((int)hu, 1);
      if ((l & 1) == 0){
        const unsigned pk = hu | (mate << 16);
        __hip_atomic_store((unsigned*)(hout + idx), pk,
                           __ATOMIC_RELAXED, __HIP_MEMORY_SCOPE_AGENT);
      }
      if (t == SEQn-1){
        cst[idx] = creg;                 // layer handoff / final output (kernel boundary)
        if (LAYER == 1) hf_out[idx] = hn;
      }
    }

    if (t + 1 < SEQn){
      // ---- hierarchical grid barrier: 32 padded group counters -> padded root ----
      __syncthreads();                   // drains vmcnt: h-publishes at L3; LDS free
      if (tid == 0){
        const unsigned ga = __hip_atomic_fetch_add(&bar[bgrp*16], 1u,
                              __ATOMIC_RELAXED, __HIP_MEMORY_SCOPE_AGENT);
        if (ga == (unsigned)(t*8 + 7)){                  // last of 8 in this group
          const unsigned ra = __hip_atomic_fetch_add(&bar[512], 1u,
                                __ATOMIC_RELAXED, __HIP_MEMORY_SCOPE_AGENT);
          if (ra == (unsigned)(t*32 + 31))               // last of 32 groups
            __hip_atomic_store(&bar[528], (unsigned)(t+1),
                               __ATOMIC_RELAXED, __HIP_MEMORY_SCOPE_AGENT);
        }
      }
      if constexpr (LAYER == 1){
        // next step's h0 = ring slot t+2: written by the PREVIOUS kernel -> stable
        const unsigned short* A1n = hring + (size_t)(t+2)*BH;
        stage(0, 512, 6, A1n, A1n);
        stage(1, 512, 6, A1n, A1n);
      } else {
        stage(NCH-1, 128, 4, A1, xpp + (size_t)(t+1)*Bsz*NUMS);   // x static
      }
      if (tid == 0){
        while (__hip_atomic_load(&bar[528], __ATOMIC_RELAXED,
                                 __HIP_MEMORY_SCOPE_AGENT) < (unsigned)(t+1))
          __builtin_amdgcn_s_sleep(1);
      }
      __syncthreads();                   // exit: also drains the prefetch issued above
    }
  }
}

// ---- final FC + copy h,c to d_out ----
__global__ __launch_bounds__(256)
void fc_out_kernel(const float* __restrict__ hf, const float* __restrict__ cst,
                   const float* __restrict__ fcw, const float* __restrict__ fcb,
                   float* __restrict__ dout){
  __shared__ float hrow[Hn];
  const int b = blockIdx.x, tid = threadIdx.x;
  for (int i = tid; i < Hn; i += 256) hrow[i] = hf[(size_t)b*Hn + i];
  __syncthreads();
  if (tid < PRED){
    float a = fcb[tid];
    for (int k = 0; k < Hn; k++) a += hrow[k] * fcw[(size_t)k*PRED + tid];
    dout[(size_t)b*PRED + tid] = tanhf(a);
  }
  for (int i = tid; i < Hn; i += 256){
    dout[Bsz*PRED + (size_t)b*Hn + i] = hf[(size_t)b*Hn + i];
    dout[Bsz*PRED + (size_t)Bsz*Hn + (size_t)b*Hn + i] = cst[(size_t)b*Hn + i];
  }
}

extern "C" void kernel_launch(void* const* d_in, const int* in_sizes, int n_in,
                              void* d_out, int out_size, void* d_ws, size_t ws_size,
                              hipStream_t stream){
  const float* x   = (const float*)d_in[0];
  const float* W0  = (const float*)d_in[1];
  const float* b0  = (const float*)d_in[2];
  const float* W1  = (const float*)d_in[3];
  const float* b1  = (const float*)d_in[4];
  const float* fcw = (const float*)d_in[5];
  const float* fcb = (const float*)d_in[6];
  float* dout = (float*)d_out;

  char* p = (char*)d_ws;
  auto alloc = [&](size_t bytes)->void*{
    void* r = (void*)p; p += (bytes + 255) & ~(size_t)255; return r;
  };
  // base footprint ~103.5 MB (proven); +67 MB h1 ring only if workspace allows
  unsigned short* xp   = (unsigned short*)alloc((size_t)SEQn*Bsz*NUMS*2);      // 8.4 MB
  unsigned short* Wpk0 = (unsigned short*)alloc((size_t)256*36*64*8*2);        // 9.4 MB
  unsigned short* Wpk1 = (unsigned short*)alloc((size_t)256*64*64*8*2);        // 16.8 MB
  unsigned short* H0   = (unsigned short*)alloc((size_t)(SEQn+1)*BH*2);        // 67.4 MB
  float* cst = (float*)alloc((size_t)BH*4);                                    // 0.5 MB
  float* hf  = (float*)alloc((size_t)BH*4);                                    // 0.5 MB
  unsigned* bars = (unsigned*)alloc((size_t)2048*sizeof(unsigned));            // 8 KB

  const bool big = ws_size >= (size_t)176*1024*1024;   // room for write-once h1 ring?
  unsigned short* h1b;
  if (big) h1b = (unsigned short*)alloc((size_t)SEQn*BH*2);                    // 67.1 MB
  else     h1b = (unsigned short*)alloc((size_t)2*BH*2);                       // 0.5 MB

  pack_x_kernel<<<dim3(SEQn/64, NUMS/64, Bsz), dim3(256), 0, stream>>>(x, xp);
  // W0 packed K order: [h rows 128..1151 -> kst 0..31][x rows 0..127 -> kst 32..35]
  pack_w_kernel<<<dim3((256*32*64 + 255)/256), dim3(256), 0, stream>>>(W0, Wpk0, 32, 128, 36, 0);
  pack_w_kernel<<<dim3((256*4*64  + 255)/256), dim3(256), 0, stream>>>(W0, Wpk0,  4,   0, 36, 32);
  // W1: rows 0..1023 = h0-part, 1024..2047 = h1-part (natural order)
  pack_w_kernel<<<dim3((256*64*64 + 255)/256), dim3(256), 0, stream>>>(W1, Wpk1, 64, 0, 64, 0);
  zero_kernel<<<dim3((Bsz*Hn + 255)/256), dim3(256), 0, stream>>>(H0, cst, bars);

  // layer 0: ONE persistent launch, 256 barriered steps (K = [h 1024 | x 128])
  persist_kernel<1024, NUMS, 1152, 0, false><<<dim3(GN), dim3(512), 0, stream>>>(
      xp, H0, nullptr, Wpk0, b0, cst, nullptr, bars);

  // layer 1: ONE persistent launch (K = [h0 1024 | h1 1024])
  if (big){
    persist_kernel<1024, Hn, 2048, 1, true><<<dim3(GN), dim3(512), 0, stream>>>(
        nullptr, H0, h1b, Wpk1, b1, cst, hf, bars + 1024);
  } else {
    persist_kernel<1024, Hn, 2048, 1, false><<<dim3(GN), dim3(512), 0, stream>>>(
        nullptr, H0, h1b, Wpk1, b1, cst, hf, bars + 1024);
  }

  fc_out_kernel<<<dim3(Bsz), dim3(256), 0, stream>>>(hf, cst, fcw, fcb, dout);
}

// Round 12
// 3372.581 us; speedup vs baseline: 1.3862x; 1.0152x over previous
//
#include <hip/hip_runtime.h>
#include <stdint.h>

#define Bsz  128
#define NUMS 128
#define SEQn 256
#define Hn   1024
#define PRED 96
#define G4H  4096
#define GN   256            // persistent grid: 256 blocks = 64 nb x 4 mb (1 per CU)
#define BH   ((size_t)Bsz*Hn)

typedef __attribute__((ext_vector_type(8))) short bf16x8;
typedef __attribute__((ext_vector_type(4))) float f32x4;

template<int N> struct IC { static constexpr int value = N; };

__device__ __forceinline__ unsigned short f2bf(float x){
  union { float f; unsigned u; } v; v.f = x;
  return (unsigned short)((v.u + 0x7FFFu + ((v.u >> 16) & 1u)) >> 16);
}
__device__ __forceinline__ float fast_tanh(float x){
  return 1.f - 2.f/(1.f + __expf(2.f*x));    // exact at +-inf; ~1e-7 rel err
}

// ---- pack x: [B][NUMS][SEQ] f32 -> xp [SEQ][B][NUMS] bf16 (LDS transpose) ----
__global__ void pack_x_kernel(const float* __restrict__ x, unsigned short* __restrict__ xp){
  __shared__ float tile[64][65];
  const int t0 = blockIdx.x * 64, n0 = blockIdx.y * 64, b = blockIdx.z;
  const int tid = threadIdx.x;
  const int c = tid & 63, r = tid >> 6;
  #pragma unroll
  for (int i = 0; i < 16; i++){
    int n = r + i*4;
    tile[n][c] = x[((size_t)b*NUMS + n0 + n)*SEQn + t0 + c];
  }
  __syncthreads();
  #pragma unroll
  for (int i = 0; i < 16; i++){
    int t = r + i*4;
    xp[((size_t)(t0+t)*Bsz + b)*NUMS + n0 + c] = f2bf(tile[c][t]);
  }
}

// ---- pack W rows into MFMA B-frag order: Wpk[cgg][kof+kst][lane][8] ----
__global__ void pack_w_kernel(const float* __restrict__ W, unsigned short* __restrict__ Wpk,
                              int KST, int row_off, int kstride, int kof){
  const int u = blockIdx.x * blockDim.x + threadIdx.x;
  if (u >= 256*KST*64) return;
  const int lane = u & 63;
  const int kst  = (u >> 6) % KST;
  const int cgg  = (u >> 6) / KST;
  const int nb = cgg >> 2, gate = cgg & 3;
  const int col = gate*Hn + nb*16 + (lane & 15);
  const int kbase = row_off + kst*32 + (lane >> 4)*8;
  unsigned short tmp[8];
  #pragma unroll
  for (int e = 0; e < 8; e++) tmp[e] = f2bf(W[(size_t)(kbase+e)*G4H + col]);
  ((ulonglong2*)Wpk)[(size_t)(cgg*kstride + kof + kst)*64 + lane] = *(const ulonglong2*)tmp;
}

__global__ void zero_kernel(unsigned short* __restrict__ h0, float* __restrict__ c,
                            unsigned* __restrict__ bars){
  int i = blockIdx.x*256 + threadIdx.x;
  if (i < Bsz*Hn){ h0[i] = 0; c[i] = 0.0f; }
  if (i < 2048) bars[i] = 0u;
}

// ---- persistent LSTM layer: fragment-major LDS (conflict-free ds_read) ----
// grid 256 = 64 nb x 4 mb (1/CU), 512 thr = 8 waves = 4 gates x 2 K-parities.
// r11 found SQ_LDS_BANK_CONFLICT = 1.5e8/dispatch (~1us/step): the row-major A-tile
// put all 64 lanes' b128 reads in 8 bank-groups (8-way). FIX: stage A-tile
// FRAGMENT-MAJOR [kst][mi][lane][16B] via per-lane global_load_lds sources (m173
// pattern): lane l's slot = its MFMA A-frag A[mi*16+(l&15)][kst*32+(l>>4)*8].
// Reads become base + l*16B -> linear, conflict-free. No XOR swizzle anywhere.
// Source offsets precomputed once (u32 regs) -> near-zero per-step address VALU.
// Barrier: r11 hierarchical 32x padded-line groups -> root -> release.
template<int K1, int S2, int KTOT, int LAYER, bool RING2>
__global__ __launch_bounds__(512, 2)
void persist_kernel(const unsigned short* __restrict__ xpp,
                    unsigned short* __restrict__ hring,
                    unsigned short* __restrict__ h1b,
                    const unsigned short* __restrict__ Wpk,
                    const float* __restrict__ bias,
                    float* __restrict__ cst,
                    float* __restrict__ hf_out,
                    unsigned* __restrict__ bar)
{
  constexpr int KST_TOT = KTOT/32;
  constexpr int HALF = KST_TOT/2;
  constexpr int NCH = (KTOT + 511)/512;                 // 3 (L0: 2 full + x) or 4 (L1)
  constexpr int NBUF = (LAYER == 0) ? 2 : 4;
  __shared__ unsigned short sa[NBUF][32*512];           // frag-major: [16kst][2mi][64][8]
  __shared__ unsigned short sxb[(LAYER == 0) ? 32*128 : 64];  // L0 x-chunk [4kst][2mi][64][8]
  __shared__ float se[2][4*32*18];                      // epilogue partials (18.4KB)

  const int tid = threadIdx.x;
  const int w = tid >> 6, l = tid & 63;
  const int blk = blockIdx.x;
  const int q = blk >> 3;
  const int nb = (blk & 7)*8 + (q & 7);   // XCD (blk&7) owns 8 consecutive nb
  const int mb = q >> 3;                  // 0..3, 32 rows each
  const int ksh = w & 1, cgi = w >> 1;    // K-parity, gate
  const int cgg = nb*4 + cgi;
  const int lrow = l & 15, lg = l >> 4;
  const int bgrp = blk >> 3;              // barrier group (32 groups of 8)

  // ---- W -> registers, once ----
  bf16x8 wreg[HALF];
  #pragma unroll
  for (int j = 0; j < HALF; j++)
    wreg[j] = *(const bf16x8*)(Wpk + ((size_t)(cgg*KST_TOT + 2*j + ksh)*64 + l)*8);

  // ---- precomputed per-lane staging source offsets (shorts, u32) ----
  // full chunk issue flat = ii*8 + w: kst_l = flat>>1, mi = flat&1.
  // src row = mb*32 + mi*16 + lrow (stride 1024 shorts); col = kst_l*32 + lg*8.
  unsigned offA[4];
  #pragma unroll
  for (int ii = 0; ii < 4; ii++){
    const int flat = ii*8 + w;
    const int kst_l = flat >> 1, mi = flat & 1;
    offA[ii] = (unsigned)((mb*32 + mi*16 + lrow)*1024 + kst_l*32 + lg*8);
  }
  const unsigned offX = (unsigned)((mb*32 + (w & 1)*16 + lrow)*S2 + (w >> 1)*32 + lg*8);

  // fixed per-thread epilogue element; c stays in a register across steps
  const int erow = tid >> 4, ejj = tid & 15;
  const int R = mb*32 + erow;
  const int J = nb*16 + ejj;
  const size_t idx = (size_t)R*Hn + J;
  float creg = (LAYER == 0) ? 0.f : cst[idx];

  // stage full 512-col chunk ch from region tile base (row stride 1024 shorts)
  auto stageF = [&](auto CHC, const unsigned short* tilebase){
    constexpr int ch = decltype(CHC)::value;
    constexpr bool coh = (LAYER == 1 && !RING2 && ch >= 2);   // h1 ping-pong: L3-coherent
    const unsigned short* b2 = tilebase + (ch & 1)*512;       // second chunk of region
    #pragma unroll
    for (int ii = 0; ii < 4; ii++){
      const unsigned short* src = b2 + offA[ii];
      if constexpr (coh)
        __builtin_amdgcn_global_load_lds(
          (const __attribute__((address_space(1))) void*)src,
          (__attribute__((address_space(3))) void*)&sa[ch][(ii*8 + w)*512], 16, 0, 17);
      else
        __builtin_amdgcn_global_load_lds(
          (const __attribute__((address_space(1))) void*)src,
          (__attribute__((address_space(3))) void*)&sa[ch][(ii*8 + w)*512], 16, 0, 0);
    }
  };
  auto stageX = [&](const unsigned short* xbase){             // L0 x-chunk: 1 issue/wave
    __builtin_amdgcn_global_load_lds(
      (const __attribute__((address_space(1))) void*)(xbase + offX),
      (__attribute__((address_space(3))) void*)&sxb[w*512], 16, 0, 0);
  };

  for (int t = 0; t < SEQn; ++t){
    #pragma unroll
    for (int j = 0; j < HALF; j++) asm volatile("" : "+v"(wreg[j]));  // keep W live

    const unsigned short* A1;
    const unsigned short* A2;
    unsigned short* hout;
    if (LAYER == 0){
      A1   = hring + (size_t)t*BH;                           // h0_{t-1}
      A2   = xpp + (size_t)t*Bsz*NUMS;                       // x_t (static)
      hout = hring + (size_t)(t+1)*BH;
    } else {
      A1   = hring + (size_t)(t+1)*BH;                       // h0_t (prev kernel output)
      A2   = (t == 0) ? (hring + (size_t)SEQn*BH)
                      : (h1b + (size_t)(RING2 ? (t-1) : ((t-1)&1))*BH);
      hout = h1b + (size_t)(RING2 ? t : (t&1))*BH;
    }

    f32x4 acc2[2] = {{0.f,0.f,0.f,0.f},{0.f,0.f,0.f,0.f}};

    // conflict-free compute: af reads are linear in lane
    auto comp = [&](auto CHC){
      constexpr int ch = decltype(CHC)::value;
      if constexpr (ch < NCH){
        constexpr bool isx = (LAYER == 0 && ch == NCH-1);
        constexpr int nksl = isx ? 2 : 8;
        const unsigned short* ab = isx ? sxb : sa[ch];
        #pragma unroll
        for (int ksl = 0; ksl < nksl; ksl++){
          const int klocal = ksl*2 + ksh;
          const int wj = isx ? (16 + ksl) : (ch*8 + ksl);
          bf16x8 af0 = *(const bf16x8*)&ab[((klocal*2 + 0)*64 + l)*8];
          bf16x8 af1 = *(const bf16x8*)&ab[((klocal*2 + 1)*64 + l)*8];
          acc2[0] = __builtin_amdgcn_mfma_f32_16x16x32_bf16(af0, wreg[wj], acc2[0], 0, 0, 0);
          acc2[1] = __builtin_amdgcn_mfma_f32_16x16x32_bf16(af1, wreg[wj], acc2[1], 0, 0, 0);
        }
      }
    };

    if (t == 0){
      // prologue: everything cold — issue all, one sync, compute all
      stageF(IC<0>{}, A1); stageF(IC<1>{}, A1);
      if constexpr (LAYER == 1){ stageF(IC<2>{}, A2); stageF(IC<3>{}, A2); }
      else                       stageX(A2);
      __syncthreads();
      comp(IC<0>{}); comp(IC<1>{}); comp(IC<2>{}); comp(IC<3>{});
    } else if constexpr (LAYER == 1){
      // ch0,ch1 (h0) resident from in-barrier prefetch (drained at barrier exit)
      stageF(IC<2>{}, A2); stageF(IC<3>{}, A2);             // h1 reads fly...
      comp(IC<0>{}); comp(IC<1>{});                         // ...under h0 compute
      __syncthreads();                                      // waits ch2,ch3
      comp(IC<2>{}); comp(IC<3>{});
    } else {
      // xb resident from in-barrier prefetch
      stageF(IC<0>{}, A1); stageF(IC<1>{}, A1);             // h reads fly...
      comp(IC<2>{});                                        // ...under x compute
      __syncthreads();                                      // waits ch0,ch1
      comp(IC<0>{}); comp(IC<1>{});
    }

    {   // write partials: [ksh][gate*32 + row][col]
      #pragma unroll
      for (int mi = 0; mi < 2; mi++)
        #pragma unroll
        for (int r = 0; r < 4; r++){
          const int row2 = mi*16 + lg*4 + r;
          se[ksh][(cgi*32 + row2)*18 + lrow] = acc2[mi][r];
        }
    }
    __syncthreads();
    {
      float zi = se[0][(0*32+erow)*18 + ejj] + se[1][(0*32+erow)*18 + ejj];
      float zf = se[0][(1*32+erow)*18 + ejj] + se[1][(1*32+erow)*18 + ejj];
      float zo = se[0][(2*32+erow)*18 + ejj] + se[1][(2*32+erow)*18 + ejj];
      float zg = se[0][(3*32+erow)*18 + ejj] + se[1][(3*32+erow)*18 + ejj];
      zi += bias[0*Hn + J]; zf += bias[1*Hn + J];
      zo += bias[2*Hn + J]; zg += bias[3*Hn + J];
      const float gi = 1.f/(1.f + __expf(-zi));
      const float gf = 1.f/(1.f + __expf(-zf));
      const float go = 1.f/(1.f + __expf(-zo));
      const float gg = fast_tanh(zg);
      creg = gf * creg + gi * gg;
      const float hn = go * fast_tanh(creg);
      // publish h at agent scope (sc1 -> L3), packed 2x bf16 per dword
      const unsigned hu   = (unsigned)f2bf(hn);
      const unsigned mate = (unsigned)__shfl_xor((int)hu, 1);
      if ((l & 1) == 0){
        const unsigned pk = hu | (mate << 16);
        __hip_atomic_store((unsigned*)(hout + idx), pk,
                           __ATOMIC_RELAXED, __HIP_MEMORY_SCOPE_AGENT);
      }
      if (t == SEQn-1){
        cst[idx] = creg;                 // layer handoff / final output (kernel boundary)
        if (LAYER == 1) hf_out[idx] = hn;
      }
    }

    if (t + 1 < SEQn){
      // ---- hierarchical grid barrier: 32 padded group counters -> padded root ----
      __syncthreads();                   // drains vmcnt: h-publishes at L3; LDS free
      if (tid == 0){
        const unsigned ga = __hip_atomic_fetch_add(&bar[bgrp*16], 1u,
                              __ATOMIC_RELAXED, __HIP_MEMORY_SCOPE_AGENT);
        if (ga == (unsigned)(t*8 + 7)){                  // last of 8 in this group
          const unsigned ra = __hip_atomic_fetch_add(&bar[512], 1u,
                                __ATOMIC_RELAXED, __HIP_MEMORY_SCOPE_AGENT);
          if (ra == (unsigned)(t*32 + 31))               // last of 32 groups
            __hip_atomic_store(&bar[528], (unsigned)(t+1),
                               __ATOMIC_RELAXED, __HIP_MEMORY_SCOPE_AGENT);
        }
      }
      if constexpr (LAYER == 1){
        // next step's h0 = ring slot t+2: written by the PREVIOUS kernel -> stable
        const unsigned short* A1n = hring + (size_t)(t+2)*BH;
        stageF(IC<0>{}, A1n);
        stageF(IC<1>{}, A1n);
      } else {
        stageX(xpp + (size_t)(t+1)*Bsz*NUMS);            // x static
      }
      if (tid == 0){
        while (__hip_atomic_load(&bar[528], __ATOMIC_RELAXED,
                                 __HIP_MEMORY_SCOPE_AGENT) < (unsigned)(t+1))
          __builtin_amdgcn_s_sleep(1);
      }
      __syncthreads();                   // exit: also drains the prefetch issued above
    }
  }
}

// ---- final FC + copy h,c to d_out ----
__global__ __launch_bounds__(256)
void fc_out_kernel(const float* __restrict__ hf, const float* __restrict__ cst,
                   const float* __restrict__ fcw, const float* __restrict__ fcb,
                   float* __restrict__ dout){
  __shared__ float hrow[Hn];
  const int b = blockIdx.x, tid = threadIdx.x;
  for (int i = tid; i < Hn; i += 256) hrow[i] = hf[(size_t)b*Hn + i];
  __syncthreads();
  if (tid < PRED){
    float a = fcb[tid];
    for (int k = 0; k < Hn; k++) a += hrow[k] * fcw[(size_t)k*PRED + tid];
    dout[(size_t)b*PRED + tid] = tanhf(a);
  }
  for (int i = tid; i < Hn; i += 256){
    dout[Bsz*PRED + (size_t)b*Hn + i] = hf[(size_t)b*Hn + i];
    dout[Bsz*PRED + (size_t)Bsz*Hn + (size_t)b*Hn + i] = cst[(size_t)b*Hn + i];
  }
}

extern "C" void kernel_launch(void* const* d_in, const int* in_sizes, int n_in,
                              void* d_out, int out_size, void* d_ws, size_t ws_size,
                              hipStream_t stream){
  const float* x   = (const float*)d_in[0];
  const float* W0  = (const float*)d_in[1];
  const float* b0  = (const float*)d_in[2];
  const float* W1  = (const float*)d_in[3];
  const float* b1  = (const float*)d_in[4];
  const float* fcw = (const float*)d_in[5];
  const float* fcb = (const float*)d_in[6];
  float* dout = (float*)d_out;

  char* p = (char*)d_ws;
  auto alloc = [&](size_t bytes)->void*{
    void* r = (void*)p; p += (bytes + 255) & ~(size_t)255; return r;
  };
  // base footprint ~103.5 MB (proven); +67 MB h1 ring only if workspace allows
  unsigned short* xp   = (unsigned short*)alloc((size_t)SEQn*Bsz*NUMS*2);      // 8.4 MB
  unsigned short* Wpk0 = (unsigned short*)alloc((size_t)256*36*64*8*2);        // 9.4 MB
  unsigned short* Wpk1 = (unsigned short*)alloc((size_t)256*64*64*8*2);        // 16.8 MB
  unsigned short* H0   = (unsigned short*)alloc((size_t)(SEQn+1)*BH*2);        // 67.4 MB
  float* cst = (float*)alloc((size_t)BH*4);                                    // 0.5 MB
  float* hf  = (float*)alloc((size_t)BH*4);                                    // 0.5 MB
  unsigned* bars = (unsigned*)alloc((size_t)2048*sizeof(unsigned));            // 8 KB

  const bool big = ws_size >= (size_t)176*1024*1024;   // room for write-once h1 ring?
  unsigned short* h1b;
  if (big) h1b = (unsigned short*)alloc((size_t)SEQn*BH*2);                    // 67.1 MB
  else     h1b = (unsigned short*)alloc((size_t)2*BH*2);                       // 0.5 MB

  pack_x_kernel<<<dim3(SEQn/64, NUMS/64, Bsz), dim3(256), 0, stream>>>(x, xp);
  // W0 packed K order: [h rows 128..1151 -> kst 0..31][x rows 0..127 -> kst 32..35]
  pack_w_kernel<<<dim3((256*32*64 + 255)/256), dim3(256), 0, stream>>>(W0, Wpk0, 32, 128, 36, 0);
  pack_w_kernel<<<dim3((256*4*64  + 255)/256), dim3(256), 0, stream>>>(W0, Wpk0,  4,   0, 36, 32);
  // W1: rows 0..1023 = h0-part, 1024..2047 = h1-part (natural order)
  pack_w_kernel<<<dim3((256*64*64 + 255)/256), dim3(256), 0, stream>>>(W1, Wpk1, 64, 0, 64, 0);
  zero_kernel<<<dim3((Bsz*Hn + 255)/256), dim3(256), 0, stream>>>(H0, cst, bars);

  // layer 0: ONE persistent launch, 256 barriered steps (K = [h 1024 | x 128])
  persist_kernel<1024, NUMS, 1152, 0, false><<<dim3(GN), dim3(512), 0, stream>>>(
      xp, H0, nullptr, Wpk0, b0, cst, nullptr, bars);

  // layer 1: ONE persistent launch (K = [h0 1024 | h1 1024])
  if (big){
    persist_kernel<1024, Hn, 2048, 1, true><<<dim3(GN), dim3(512), 0, stream>>>(
        nullptr, H0, h1b, Wpk1, b1, cst, hf, bars + 1024);
  } else {
    persist_kernel<1024, Hn, 2048, 1, false><<<dim3(GN), dim3(512), 0, stream>>>(
        nullptr, H0, h1b, Wpk1, b1, cst, hf, bars + 1024);
  }

  fc_out_kernel<<<dim3(Bsz), dim3(256), 0, stream>>>(hf, cst, fcw, fcb, dout);
}

// Round 13
// 2973.818 us; speedup vs baseline: 1.5721x; 1.1341x over previous
//
#include <hip/hip_runtime.h>
#include <stdint.h>

#define Bsz  128
#define NUMS 128
#define SEQn 256
#define Hn   1024
#define PRED 96
#define G4H  4096
#define GN   256            // persistent grid: 256 blocks = 64 nb x 4 mb (1 per CU)
#define BH   ((size_t)Bsz*Hn)

typedef __attribute__((ext_vector_type(8))) short bf16x8;
typedef __attribute__((ext_vector_type(4))) float f32x4;

template<int N> struct IC { static constexpr int value = N; };

__device__ __forceinline__ unsigned short f2bf(float x){
  union { float f; unsigned u; } v; v.f = x;
  return (unsigned short)((v.u + 0x7FFFu + ((v.u >> 16) & 1u)) >> 16);
}
__device__ __forceinline__ float fast_tanh(float x){
  return 1.f - 2.f/(1.f + __expf(2.f*x));    // exact at +-inf; ~1e-7 rel err
}

// ---- pack x: [B][NUMS][SEQ] f32 -> xp [SEQ][B][NUMS] bf16 (LDS transpose) ----
__global__ void pack_x_kernel(const float* __restrict__ x, unsigned short* __restrict__ xp){
  __shared__ float tile[64][65];
  const int t0 = blockIdx.x * 64, n0 = blockIdx.y * 64, b = blockIdx.z;
  const int tid = threadIdx.x;
  const int c = tid & 63, r = tid >> 6;
  #pragma unroll
  for (int i = 0; i < 16; i++){
    int n = r + i*4;
    tile[n][c] = x[((size_t)b*NUMS + n0 + n)*SEQn + t0 + c];
  }
  __syncthreads();
  #pragma unroll
  for (int i = 0; i < 16; i++){
    int t = r + i*4;
    xp[((size_t)(t0+t)*Bsz + b)*NUMS + n0 + c] = f2bf(tile[c][t]);
  }
}

// ---- pack W rows into MFMA B-frag order: Wpk[cgg][kof+kst][lane][8] ----
__global__ void pack_w_kernel(const float* __restrict__ W, unsigned short* __restrict__ Wpk,
                              int KST, int row_off, int kstride, int kof){
  const int u = blockIdx.x * blockDim.x + threadIdx.x;
  if (u >= 256*KST*64) return;
  const int lane = u & 63;
  const int kst  = (u >> 6) % KST;
  const int cgg  = (u >> 6) / KST;
  const int nb = cgg >> 2, gate = cgg & 3;
  const int col = gate*Hn + nb*16 + (lane & 15);
  const int kbase = row_off + kst*32 + (lane >> 4)*8;
  unsigned short tmp[8];
  #pragma unroll
  for (int e = 0; e < 8; e++) tmp[e] = f2bf(W[(size_t)(kbase+e)*G4H + col]);
  ((ulonglong2*)Wpk)[(size_t)(cgg*kstride + kof + kst)*64 + lane] = *(const ulonglong2*)tmp;
}

__global__ void zero_kernel(unsigned short* __restrict__ h0, float* __restrict__ c,
                            unsigned* __restrict__ bars){
  int i = blockIdx.x*256 + threadIdx.x;
  if (i < Bsz*Hn){ h0[i] = 0; c[i] = 0.0f; }
  if (i < 2048) bars[i] = 0u;
}

// ---- persistent LSTM layer: r12 structure + PER-MB dependency-exact barrier ----
// grid 256 = 64 nb x 4 mb (1/CU), 512 thr = 8 waves = 4 gates x 2 K-parities.
// DATAFLOW FACT: block (nb,mb) reads ONLY h rows [mb*32, mb*32+32) — produced by the
// 64 same-mb blocks; h1 ping-pong rows are mb-partitioned too; W slices are per-nb
// (mb-independent). So the step barrier only needs the 64-block mb-group. r7/r9's
// per-mb attempts were confounded (WAITV spills / "+a" forcing / shared cache line);
// this is the clean A/B vs r12: barrier = 4 independent per-mb hierarchical barriers,
// every counter on its own 64B line. bars layout per mb m (u32 idx, base mb*256):
// group g arrivals at [g*16] g=0..7 (8 blocks each), root at [128], release at [144].
template<int K1, int S2, int KTOT, int LAYER, bool RING2>
__global__ __launch_bounds__(512, 2)
void persist_kernel(const unsigned short* __restrict__ xpp,
                    unsigned short* __restrict__ hring,
                    unsigned short* __restrict__ h1b,
                    const unsigned short* __restrict__ Wpk,
                    const float* __restrict__ bias,
                    float* __restrict__ cst,
                    float* __restrict__ hf_out,
                    unsigned* __restrict__ bar)
{
  constexpr int KST_TOT = KTOT/32;
  constexpr int HALF = KST_TOT/2;
  constexpr int NCH = (KTOT + 511)/512;                 // 3 (L0: 2 full + x) or 4 (L1)
  constexpr int NBUF = (LAYER == 0) ? 2 : 4;
  __shared__ unsigned short sa[NBUF][32*512];           // frag-major: [16kst][2mi][64][8]
  __shared__ unsigned short sxb[(LAYER == 0) ? 32*128 : 64];  // L0 x-chunk [4kst][2mi][64][8]
  __shared__ float se[2][4*32*18];                      // epilogue partials (18.4KB)

  const int tid = threadIdx.x;
  const int w = tid >> 6, l = tid & 63;
  const int blk = blockIdx.x;
  const int q = blk >> 3;
  const int nb = (blk & 7)*8 + (q & 7);   // XCD (blk&7) owns 8 consecutive nb
  const int mb = q >> 3;                  // 0..3 : the independent dependency group
  const int ksh = w & 1, cgi = w >> 1;    // K-parity, gate
  const int cgg = nb*4 + cgi;
  const int lrow = l & 15, lg = l >> 4;
  const int sg = (blk >> 3) & 7;          // sub-group (8 blocks) within my mb-group
  unsigned* mbar = bar + mb*256;          // this mb-group's barrier block

  // ---- W -> registers, once ----
  bf16x8 wreg[HALF];
  #pragma unroll
  for (int j = 0; j < HALF; j++)
    wreg[j] = *(const bf16x8*)(Wpk + ((size_t)(cgg*KST_TOT + 2*j + ksh)*64 + l)*8);

  // ---- precomputed per-lane staging source offsets (shorts, u32) ----
  unsigned offA[4];
  #pragma unroll
  for (int ii = 0; ii < 4; ii++){
    const int flat = ii*8 + w;
    const int kst_l = flat >> 1, mi = flat & 1;
    offA[ii] = (unsigned)((mb*32 + mi*16 + lrow)*1024 + kst_l*32 + lg*8);
  }
  const unsigned offX = (unsigned)((mb*32 + (w & 1)*16 + lrow)*S2 + (w >> 1)*32 + lg*8);

  // fixed per-thread epilogue element; c stays in a register across steps
  const int erow = tid >> 4, ejj = tid & 15;
  const int R = mb*32 + erow;
  const int J = nb*16 + ejj;
  const size_t idx = (size_t)R*Hn + J;
  float creg = (LAYER == 0) ? 0.f : cst[idx];

  // stage full 512-col chunk ch from region tile base (row stride 1024 shorts)
  auto stageF = [&](auto CHC, const unsigned short* tilebase){
    constexpr int ch = decltype(CHC)::value;
    constexpr bool coh = (LAYER == 1 && !RING2 && ch >= 2);   // h1 ping-pong: L3-coherent
    const unsigned short* b2 = tilebase + (ch & 1)*512;       // second chunk of region
    #pragma unroll
    for (int ii = 0; ii < 4; ii++){
      const unsigned short* src = b2 + offA[ii];
      if constexpr (coh)
        __builtin_amdgcn_global_load_lds(
          (const __attribute__((address_space(1))) void*)src,
          (__attribute__((address_space(3))) void*)&sa[ch][(ii*8 + w)*512], 16, 0, 17);
      else
        __builtin_amdgcn_global_load_lds(
          (const __attribute__((address_space(1))) void*)src,
          (__attribute__((address_space(3))) void*)&sa[ch][(ii*8 + w)*512], 16, 0, 0);
    }
  };
  auto stageX = [&](const unsigned short* xbase){             // L0 x-chunk: 1 issue/wave
    __builtin_amdgcn_global_load_lds(
      (const __attribute__((address_space(1))) void*)(xbase + offX),
      (__attribute__((address_space(3))) void*)&sxb[w*512], 16, 0, 0);
  };

  for (int t = 0; t < SEQn; ++t){
    #pragma unroll
    for (int j = 0; j < HALF; j++) asm volatile("" : "+v"(wreg[j]));  // keep W live

    const unsigned short* A1;
    const unsigned short* A2;
    unsigned short* hout;
    if (LAYER == 0){
      A1   = hring + (size_t)t*BH;                           // h0_{t-1}
      A2   = xpp + (size_t)t*Bsz*NUMS;                       // x_t (static)
      hout = hring + (size_t)(t+1)*BH;
    } else {
      A1   = hring + (size_t)(t+1)*BH;                       // h0_t (prev kernel output)
      A2   = (t == 0) ? (hring + (size_t)SEQn*BH)
                      : (h1b + (size_t)(RING2 ? (t-1) : ((t-1)&1))*BH);
      hout = h1b + (size_t)(RING2 ? t : (t&1))*BH;
    }

    f32x4 acc2[2] = {{0.f,0.f,0.f,0.f},{0.f,0.f,0.f,0.f}};

    // conflict-free compute: af reads are linear in lane
    auto comp = [&](auto CHC){
      constexpr int ch = decltype(CHC)::value;
      if constexpr (ch < NCH){
        constexpr bool isx = (LAYER == 0 && ch == NCH-1);
        constexpr int nksl = isx ? 2 : 8;
        const unsigned short* ab = isx ? sxb : sa[ch];
        #pragma unroll
        for (int ksl = 0; ksl < nksl; ksl++){
          const int klocal = ksl*2 + ksh;
          const int wj = isx ? (16 + ksl) : (ch*8 + ksl);
          bf16x8 af0 = *(const bf16x8*)&ab[((klocal*2 + 0)*64 + l)*8];
          bf16x8 af1 = *(const bf16x8*)&ab[((klocal*2 + 1)*64 + l)*8];
          acc2[0] = __builtin_amdgcn_mfma_f32_16x16x32_bf16(af0, wreg[wj], acc2[0], 0, 0, 0);
          acc2[1] = __builtin_amdgcn_mfma_f32_16x16x32_bf16(af1, wreg[wj], acc2[1], 0, 0, 0);
        }
      }
    };

    if (t == 0){
      // prologue: everything cold — issue all, one sync, compute all
      stageF(IC<0>{}, A1); stageF(IC<1>{}, A1);
      if constexpr (LAYER == 1){ stageF(IC<2>{}, A2); stageF(IC<3>{}, A2); }
      else                       stageX(A2);
      __syncthreads();
      comp(IC<0>{}); comp(IC<1>{}); comp(IC<2>{}); comp(IC<3>{});
    } else if constexpr (LAYER == 1){
      // ch0,ch1 (h0) resident from in-barrier prefetch (drained at barrier exit)
      stageF(IC<2>{}, A2); stageF(IC<3>{}, A2);             // h1 reads fly...
      comp(IC<0>{}); comp(IC<1>{});                         // ...under h0 compute
      __syncthreads();                                      // waits ch2,ch3
      comp(IC<2>{}); comp(IC<3>{});
    } else {
      // xb resident from in-barrier prefetch
      stageF(IC<0>{}, A1); stageF(IC<1>{}, A1);             // h reads fly...
      comp(IC<2>{});                                        // ...under x compute
      __syncthreads();                                      // waits ch0,ch1
      comp(IC<0>{}); comp(IC<1>{});
    }

    {   // write partials: [ksh][gate*32 + row][col]
      #pragma unroll
      for (int mi = 0; mi < 2; mi++)
        #pragma unroll
        for (int r = 0; r < 4; r++){
          const int row2 = mi*16 + lg*4 + r;
          se[ksh][(cgi*32 + row2)*18 + lrow] = acc2[mi][r];
        }
    }
    __syncthreads();
    {
      float zi = se[0][(0*32+erow)*18 + ejj] + se[1][(0*32+erow)*18 + ejj];
      float zf = se[0][(1*32+erow)*18 + ejj] + se[1][(1*32+erow)*18 + ejj];
      float zo = se[0][(2*32+erow)*18 + ejj] + se[1][(2*32+erow)*18 + ejj];
      float zg = se[0][(3*32+erow)*18 + ejj] + se[1][(3*32+erow)*18 + ejj];
      zi += bias[0*Hn + J]; zf += bias[1*Hn + J];
      zo += bias[2*Hn + J]; zg += bias[3*Hn + J];
      const float gi = 1.f/(1.f + __expf(-zi));
      const float gf = 1.f/(1.f + __expf(-zf));
      const float go = 1.f/(1.f + __expf(-zo));
      const float gg = fast_tanh(zg);
      creg = gf * creg + gi * gg;
      const float hn = go * fast_tanh(creg);
      // publish h at agent scope (sc1 -> L3), packed 2x bf16 per dword
      const unsigned hu   = (unsigned)f2bf(hn);
      const unsigned mate = (unsigned)__shfl_xor((int)hu, 1);
      if ((l & 1) == 0){
        const unsigned pk = hu | (mate << 16);
        __hip_atomic_store((unsigned*)(hout + idx), pk,
                           __ATOMIC_RELAXED, __HIP_MEMORY_SCOPE_AGENT);
      }
      if (t == SEQn-1){
        cst[idx] = creg;                 // layer handoff / final output (kernel boundary)
        if (LAYER == 1) hf_out[idx] = hn;
      }
    }

    if (t + 1 < SEQn){
      // ---- per-mb hierarchical barrier (64 arrivals; all counters line-padded) ----
      __syncthreads();                   // drains vmcnt: h-publishes at L3; LDS free
      if (tid == 0){
        const unsigned ga = __hip_atomic_fetch_add(&mbar[sg*16], 1u,
                              __ATOMIC_RELAXED, __HIP_MEMORY_SCOPE_AGENT);
        if (ga == (unsigned)(t*8 + 7)){                  // last of 8 in my sub-group
          const unsigned ra = __hip_atomic_fetch_add(&mbar[128], 1u,
                                __ATOMIC_RELAXED, __HIP_MEMORY_SCOPE_AGENT);
          if (ra == (unsigned)(t*8 + 7))                 // last of 8 sub-groups
            __hip_atomic_store(&mbar[144], (unsigned)(t+1),
                               __ATOMIC_RELAXED, __HIP_MEMORY_SCOPE_AGENT);
        }
      }
      if constexpr (LAYER == 1){
        // next step's h0 = ring slot t+2: written by the PREVIOUS kernel -> stable
        const unsigned short* A1n = hring + (size_t)(t+2)*BH;
        stageF(IC<0>{}, A1n);
        stageF(IC<1>{}, A1n);
      } else {
        stageX(xpp + (size_t)(t+1)*Bsz*NUMS);            // x static
      }
      if (tid == 0){
        while (__hip_atomic_load(&mbar[144], __ATOMIC_RELAXED,
                                 __HIP_MEMORY_SCOPE_AGENT) < (unsigned)(t+1))
          __builtin_amdgcn_s_sleep(1);
      }
      __syncthreads();                   // exit: also drains the prefetch issued above
    }
  }
}

// ---- final FC + copy h,c to d_out ----
__global__ __launch_bounds__(256)
void fc_out_kernel(const float* __restrict__ hf, const float* __restrict__ cst,
                   const float* __restrict__ fcw, const float* __restrict__ fcb,
                   float* __restrict__ dout){
  __shared__ float hrow[Hn];
  const int b = blockIdx.x, tid = threadIdx.x;
  for (int i = tid; i < Hn; i += 256) hrow[i] = hf[(size_t)b*Hn + i];
  __syncthreads();
  if (tid < PRED){
    float a = fcb[tid];
    for (int k = 0; k < Hn; k++) a += hrow[k] * fcw[(size_t)k*PRED + tid];
    dout[(size_t)b*PRED + tid] = tanhf(a);
  }
  for (int i = tid; i < Hn; i += 256){
    dout[Bsz*PRED + (size_t)b*Hn + i] = hf[(size_t)b*Hn + i];
    dout[Bsz*PRED + (size_t)Bsz*Hn + (size_t)b*Hn + i] = cst[(size_t)b*Hn + i];
  }
}

extern "C" void kernel_launch(void* const* d_in, const int* in_sizes, int n_in,
                              void* d_out, int out_size, void* d_ws, size_t ws_size,
                              hipStream_t stream){
  const float* x   = (const float*)d_in[0];
  const float* W0  = (const float*)d_in[1];
  const float* b0  = (const float*)d_in[2];
  const float* W1  = (const float*)d_in[3];
  const float* b1  = (const float*)d_in[4];
  const float* fcw = (const float*)d_in[5];
  const float* fcb = (const float*)d_in[6];
  float* dout = (float*)d_out;

  char* p = (char*)d_ws;
  auto alloc = [&](size_t bytes)->void*{
    void* r = (void*)p; p += (bytes + 255) & ~(size_t)255; return r;
  };
  // base footprint ~103.5 MB (proven); +67 MB h1 ring only if workspace allows
  unsigned short* xp   = (unsigned short*)alloc((size_t)SEQn*Bsz*NUMS*2);      // 8.4 MB
  unsigned short* Wpk0 = (unsigned short*)alloc((size_t)256*36*64*8*2);        // 9.4 MB
  unsigned short* Wpk1 = (unsigned short*)alloc((size_t)256*64*64*8*2);        // 16.8 MB
  unsigned short* H0   = (unsigned short*)alloc((size_t)(SEQn+1)*BH*2);        // 67.4 MB
  float* cst = (float*)alloc((size_t)BH*4);                                    // 0.5 MB
  float* hf  = (float*)alloc((size_t)BH*4);                                    // 0.5 MB
  unsigned* bars = (unsigned*)alloc((size_t)2048*sizeof(unsigned));            // 8 KB

  const bool big = ws_size >= (size_t)176*1024*1024;   // room for write-once h1 ring?
  unsigned short* h1b;
  if (big) h1b = (unsigned short*)alloc((size_t)SEQn*BH*2);                    // 67.1 MB
  else     h1b = (unsigned short*)alloc((size_t)2*BH*2);                       // 0.5 MB

  pack_x_kernel<<<dim3(SEQn/64, NUMS/64, Bsz), dim3(256), 0, stream>>>(x, xp);
  // W0 packed K order: [h rows 128..1151 -> kst 0..31][x rows 0..127 -> kst 32..35]
  pack_w_kernel<<<dim3((256*32*64 + 255)/256), dim3(256), 0, stream>>>(W0, Wpk0, 32, 128, 36, 0);
  pack_w_kernel<<<dim3((256*4*64  + 255)/256), dim3(256), 0, stream>>>(W0, Wpk0,  4,   0, 36, 32);
  // W1: rows 0..1023 = h0-part, 1024..2047 = h1-part (natural order)
  pack_w_kernel<<<dim3((256*64*64 + 255)/256), dim3(256), 0, stream>>>(W1, Wpk1, 64, 0, 64, 0);
  zero_kernel<<<dim3((Bsz*Hn + 255)/256), dim3(256), 0, stream>>>(H0, cst, bars);

  // layer 0: ONE persistent launch, 256 barriered steps (K = [h 1024 | x 128])
  persist_kernel<1024, NUMS, 1152, 0, false><<<dim3(GN), dim3(512), 0, stream>>>(
      xp, H0, nullptr, Wpk0, b0, cst, nullptr, bars);

  // layer 1: ONE persistent launch (K = [h0 1024 | h1 1024])
  if (big){
    persist_kernel<1024, Hn, 2048, 1, true><<<dim3(GN), dim3(512), 0, stream>>>(
        nullptr, H0, h1b, Wpk1, b1, cst, hf, bars + 1024);
  } else {
    persist_kernel<1024, Hn, 2048, 1, false><<<dim3(GN), dim3(512), 0, stream>>>(
        nullptr, H0, h1b, Wpk1, b1, cst, hf, bars + 1024);
  }

  fc_out_kernel<<<dim3(Bsz), dim3(256), 0, stream>>>(hf, cst, fcw, fcb, dout);
}

// Round 14
// 2849.536 us; speedup vs baseline: 1.6407x; 1.0436x over previous
//
#include <hip/hip_runtime.h>
#include <stdint.h>

#define Bsz  128
#define NUMS 128
#define SEQn 256
#define Hn   1024
#define PRED 96
#define G4H  4096
#define GN   256            // persistent grid: 256 blocks = 64 nb x 4 mb (1 per CU)
#define BH   ((size_t)Bsz*Hn)

typedef __attribute__((ext_vector_type(8))) short bf16x8;
typedef __attribute__((ext_vector_type(4))) float f32x4;

template<int N> struct IC { static constexpr int value = N; };

__device__ __forceinline__ unsigned short f2bf(float x){
  union { float f; unsigned u; } v; v.f = x;
  return (unsigned short)((v.u + 0x7FFFu + ((v.u >> 16) & 1u)) >> 16);
}
__device__ __forceinline__ float fast_tanh(float x){
  return 1.f - 2.f/(1.f + __expf(2.f*x));    // exact at +-inf; ~1e-7 rel err
}

// ---- pack x: [B][NUMS][SEQ] f32 -> xp [SEQ][B][NUMS] bf16 (LDS transpose) ----
__global__ void pack_x_kernel(const float* __restrict__ x, unsigned short* __restrict__ xp){
  __shared__ float tile[64][65];
  const int t0 = blockIdx.x * 64, n0 = blockIdx.y * 64, b = blockIdx.z;
  const int tid = threadIdx.x;
  const int c = tid & 63, r = tid >> 6;
  #pragma unroll
  for (int i = 0; i < 16; i++){
    int n = r + i*4;
    tile[n][c] = x[((size_t)b*NUMS + n0 + n)*SEQn + t0 + c];
  }
  __syncthreads();
  #pragma unroll
  for (int i = 0; i < 16; i++){
    int t = r + i*4;
    xp[((size_t)(t0+t)*Bsz + b)*NUMS + n0 + c] = f2bf(tile[c][t]);
  }
}

// ---- pack W rows into MFMA B-frag order: Wpk[cgg][kof+kst][lane][8] ----
__global__ void pack_w_kernel(const float* __restrict__ W, unsigned short* __restrict__ Wpk,
                              int KST, int row_off, int kstride, int kof){
  const int u = blockIdx.x * blockDim.x + threadIdx.x;
  if (u >= 256*KST*64) return;
  const int lane = u & 63;
  const int kst  = (u >> 6) % KST;
  const int cgg  = (u >> 6) / KST;
  const int nb = cgg >> 2, gate = cgg & 3;
  const int col = gate*Hn + nb*16 + (lane & 15);
  const int kbase = row_off + kst*32 + (lane >> 4)*8;
  unsigned short tmp[8];
  #pragma unroll
  for (int e = 0; e < 8; e++) tmp[e] = f2bf(W[(size_t)(kbase+e)*G4H + col]);
  ((ulonglong2*)Wpk)[(size_t)(cgg*kstride + kof + kst)*64 + lane] = *(const ulonglong2*)tmp;
}

__global__ void zero_kernel(unsigned short* __restrict__ h0, float* __restrict__ c,
                            unsigned* __restrict__ bars){
  int i = blockIdx.x*256 + threadIdx.x;
  if (i < Bsz*Hn){ h0[i] = 0; c[i] = 0.0f; }
  if (i < 2048) bars[i] = 0u;
}

// ---- persistent LSTM layer: r13 structure, barrier -> producer-counter FLAGS ----
// grid 256 = 64 nb x 4 mb (1/CU), 512 thr = 8 waves = 4 gates x 2 K-parities.
// r13's per-mb hierarchical barrier cost ~3 serialized L3 round trips (arrival ->
// root -> release -> poll) + exit sync. DATAFLOW: consumer of column-half H only
// needs the 32 producers nb' in H done with step t-1. So: per (mb, half) ONE
// monotonic padded counter (own 64B line). Producer fetch_adds it after its
// publish-drain sync; consumers POLL it directly (>= 32*t) right before staging
// that half. No root, no release, no exit sync. Skew bound: epilogue t requires
// both halves >= 32t -> all 64 mb-blocks finished t-1 -> ping-pong overwrite of
// h1_{t-2}'s slot is safe (its readers ran in step t-1). Next-step stable
// prefetch (h0 slot t+2 / x_{t+1}) issues under the epilogue; the pre-arrival
// sync drains it together with the h-publish.
// bars layout (u32): mb m half h -> [m*64 + h*16]. L0 base 0, L1 base 1024.
template<int K1, int S2, int KTOT, int LAYER, bool RING2>
__global__ __launch_bounds__(512, 2)
void persist_kernel(const unsigned short* __restrict__ xpp,
                    unsigned short* __restrict__ hring,
                    unsigned short* __restrict__ h1b,
                    const unsigned short* __restrict__ Wpk,
                    const float* __restrict__ bias,
                    float* __restrict__ cst,
                    float* __restrict__ hf_out,
                    unsigned* __restrict__ bar)
{
  constexpr int KST_TOT = KTOT/32;
  constexpr int HALF = KST_TOT/2;
  constexpr int NCH = (KTOT + 511)/512;                 // 3 (L0: 2 full + x) or 4 (L1)
  constexpr int NBUF = (LAYER == 0) ? 2 : 4;
  __shared__ unsigned short sa[NBUF][32*512];           // frag-major: [16kst][2mi][64][8]
  __shared__ unsigned short sxb[(LAYER == 0) ? 32*128 : 64];  // L0 x-chunk
  __shared__ float se[2][4*32*18];                      // epilogue partials (18.4KB)

  const int tid = threadIdx.x;
  const int w = tid >> 6, l = tid & 63;
  const int blk = blockIdx.x;
  const int q = blk >> 3;
  const int nb = (blk & 7)*8 + (q & 7);   // XCD (blk&7) owns 8 consecutive nb
  const int mb = q >> 3;                  // 0..3 : the independent dependency group
  const int ksh = w & 1, cgi = w >> 1;    // K-parity, gate
  const int cgg = nb*4 + cgi;
  const int lrow = l & 15, lg = l >> 4;
  const int myhalf = nb >> 5;             // which column-half this block produces
  unsigned* mycnt = bar + mb*64;          // two padded counters: +0 (halfA), +16 (halfB)

  // ---- W -> registers, once ----
  bf16x8 wreg[HALF];
  #pragma unroll
  for (int j = 0; j < HALF; j++)
    wreg[j] = *(const bf16x8*)(Wpk + ((size_t)(cgg*KST_TOT + 2*j + ksh)*64 + l)*8);

  // ---- precomputed per-lane staging source offsets (shorts, u32) ----
  unsigned offA[4];
  #pragma unroll
  for (int ii = 0; ii < 4; ii++){
    const int flat = ii*8 + w;
    const int kst_l = flat >> 1, mi = flat & 1;
    offA[ii] = (unsigned)((mb*32 + mi*16 + lrow)*1024 + kst_l*32 + lg*8);
  }
  const unsigned offX = (unsigned)((mb*32 + (w & 1)*16 + lrow)*S2 + (w >> 1)*32 + lg*8);

  // fixed per-thread epilogue element; c stays in a register across steps
  const int erow = tid >> 4, ejj = tid & 15;
  const int R = mb*32 + erow;
  const int J = nb*16 + ejj;
  const size_t idx = (size_t)R*Hn + J;
  float creg = (LAYER == 0) ? 0.f : cst[idx];

  // stage full 512-col chunk ch from region tile base (row stride 1024 shorts)
  auto stageF = [&](auto CHC, const unsigned short* tilebase){
    constexpr int ch = decltype(CHC)::value;
    constexpr bool coh = (LAYER == 1 && !RING2 && ch >= 2);   // h1 ping-pong: L3-coherent
    const unsigned short* b2 = tilebase + (ch & 1)*512;       // second chunk of region
    #pragma unroll
    for (int ii = 0; ii < 4; ii++){
      const unsigned short* src = b2 + offA[ii];
      if constexpr (coh)
        __builtin_amdgcn_global_load_lds(
          (const __attribute__((address_space(1))) void*)src,
          (__attribute__((address_space(3))) void*)&sa[ch][(ii*8 + w)*512], 16, 0, 17);
      else
        __builtin_amdgcn_global_load_lds(
          (const __attribute__((address_space(1))) void*)src,
          (__attribute__((address_space(3))) void*)&sa[ch][(ii*8 + w)*512], 16, 0, 0);
    }
  };
  auto stageX = [&](const unsigned short* xbase){             // L0 x-chunk: 1 issue/wave
    __builtin_amdgcn_global_load_lds(
      (const __attribute__((address_space(1))) void*)(xbase + offX),
      (__attribute__((address_space(3))) void*)&sxb[w*512], 16, 0, 0);
  };
  // poll a half-counter until its 32 producers finished step t-1 (target = 32*t)
  auto pollHalf = [&](int half, unsigned target){
    const unsigned* cw = mycnt + half*16;
    while (__hip_atomic_load(cw, __ATOMIC_RELAXED, __HIP_MEMORY_SCOPE_AGENT) < target)
      __builtin_amdgcn_s_sleep(1);
  };

  for (int t = 0; t < SEQn; ++t){
    #pragma unroll
    for (int j = 0; j < HALF; j++) asm volatile("" : "+v"(wreg[j]));  // keep W live

    const unsigned short* A1;
    const unsigned short* A2;
    unsigned short* hout;
    if (LAYER == 0){
      A1   = hring + (size_t)t*BH;                           // h0_{t-1}
      A2   = xpp + (size_t)t*Bsz*NUMS;                       // x_t (static)
      hout = hring + (size_t)(t+1)*BH;
    } else {
      A1   = hring + (size_t)(t+1)*BH;                       // h0_t (prev kernel output)
      A2   = (t == 0) ? (hring + (size_t)SEQn*BH)
                      : (h1b + (size_t)(RING2 ? (t-1) : ((t-1)&1))*BH);
      hout = h1b + (size_t)(RING2 ? t : (t&1))*BH;
    }

    f32x4 acc2[2] = {{0.f,0.f,0.f,0.f},{0.f,0.f,0.f,0.f}};

    // conflict-free compute: af reads are linear in lane
    auto comp = [&](auto CHC){
      constexpr int ch = decltype(CHC)::value;
      if constexpr (ch < NCH){
        constexpr bool isx = (LAYER == 0 && ch == NCH-1);
        constexpr int nksl = isx ? 2 : 8;
        const unsigned short* ab = isx ? sxb : sa[ch];
        #pragma unroll
        for (int ksl = 0; ksl < nksl; ksl++){
          const int klocal = ksl*2 + ksh;
          const int wj = isx ? (16 + ksl) : (ch*8 + ksl);
          bf16x8 af0 = *(const bf16x8*)&ab[((klocal*2 + 0)*64 + l)*8];
          bf16x8 af1 = *(const bf16x8*)&ab[((klocal*2 + 1)*64 + l)*8];
          acc2[0] = __builtin_amdgcn_mfma_f32_16x16x32_bf16(af0, wreg[wj], acc2[0], 0, 0, 0);
          acc2[1] = __builtin_amdgcn_mfma_f32_16x16x32_bf16(af1, wreg[wj], acc2[1], 0, 0, 0);
        }
      }
    };

    if (t == 0){
      // prologue: everything cold (sources all stable) — issue all, sync, compute all
      stageF(IC<0>{}, A1); stageF(IC<1>{}, A1);
      if constexpr (LAYER == 1){ stageF(IC<2>{}, A2); stageF(IC<3>{}, A2); }
      else                       stageX(A2);
      __syncthreads();
      comp(IC<0>{}); comp(IC<1>{}); comp(IC<2>{}); comp(IC<3>{});
    } else if constexpr (LAYER == 1){
      // fresh = h1_{t-1} (ch2: cols 0..511 <- halfA producers; ch3 <- halfB)
      pollHalf(0, 32u*(unsigned)t); stageF(IC<2>{}, A2);
      pollHalf(1, 32u*(unsigned)t); stageF(IC<3>{}, A2);
      comp(IC<0>{}); comp(IC<1>{});                         // h0, prefetched last iter
      __syncthreads();                                      // drain fresh (own vmcnt0)
      comp(IC<2>{}); comp(IC<3>{});
    } else {
      // fresh = h0_{t-1} (ch0 <- halfA, ch1 <- halfB); xb prefetched last iter
      pollHalf(0, 32u*(unsigned)t); stageF(IC<0>{}, A1);
      pollHalf(1, 32u*(unsigned)t); stageF(IC<1>{}, A1);
      comp(IC<2>{});                                        // x chunk (tiny)
      __syncthreads();                                      // drain fresh
      comp(IC<0>{}); comp(IC<1>{});
    }

    {   // write partials: [ksh][gate*32 + row][col]
      #pragma unroll
      for (int mi = 0; mi < 2; mi++)
        #pragma unroll
        for (int r = 0; r < 4; r++){
          const int row2 = mi*16 + lg*4 + r;
          se[ksh][(cgi*32 + row2)*18 + lrow] = acc2[mi][r];
        }
    }
    __syncthreads();

    // next-step STABLE prefetch issues here: overlaps the epilogue math; the
    // pre-arrival sync below drains it together with the h-publish.
    if (t + 1 < SEQn){
      if constexpr (LAYER == 1){
        const unsigned short* A1n = hring + (size_t)(t+2)*BH;   // prev-kernel data
        stageF(IC<0>{}, A1n);
        stageF(IC<1>{}, A1n);
      } else {
        stageX(xpp + (size_t)(t+1)*Bsz*NUMS);                   // x static
      }
    }

    {
      float zi = se[0][(0*32+erow)*18 + ejj] + se[1][(0*32+erow)*18 + ejj];
      float zf = se[0][(1*32+erow)*18 + ejj] + se[1][(1*32+erow)*18 + ejj];
      float zo = se[0][(2*32+erow)*18 + ejj] + se[1][(2*32+erow)*18 + ejj];
      float zg = se[0][(3*32+erow)*18 + ejj] + se[1][(3*32+erow)*18 + ejj];
      zi += bias[0*Hn + J]; zf += bias[1*Hn + J];
      zo += bias[2*Hn + J]; zg += bias[3*Hn + J];
      const float gi = 1.f/(1.f + __expf(-zi));
      const float gf = 1.f/(1.f + __expf(-zf));
      const float go = 1.f/(1.f + __expf(-zo));
      const float gg = fast_tanh(zg);
      creg = gf * creg + gi * gg;
      const float hn = go * fast_tanh(creg);
      // publish h at agent scope (sc1 -> L3), packed 2x bf16 per dword
      const unsigned hu   = (unsigned)f2bf(hn);
      const unsigned mate = (unsigned)__shfl_xor((int)hu, 1);
      if ((l & 1) == 0){
        const unsigned pk = hu | (mate << 16);
        __hip_atomic_store((unsigned*)(hout + idx), pk,
                           __ATOMIC_RELAXED, __HIP_MEMORY_SCOPE_AGENT);
      }
      if (t == SEQn-1){
        cst[idx] = creg;                 // layer handoff / final output (kernel boundary)
        if (LAYER == 1) hf_out[idx] = hn;
      }
    }

    if (t + 1 < SEQn){
      __syncthreads();                   // drain h-publish + prefetch (own vmcnt0, all waves)
      if (tid == 0)
        __hip_atomic_fetch_add(mycnt + myhalf*16, 1u,
                               __ATOMIC_RELAXED, __HIP_MEMORY_SCOPE_AGENT);
      // no exit sync: next iteration's polls gate the fresh staging directly
    }
  }
}

// ---- final FC + copy h,c to d_out ----
__global__ __launch_bounds__(256)
void fc_out_kernel(const float* __restrict__ hf, const float* __restrict__ cst,
                   const float* __restrict__ fcw, const float* __restrict__ fcb,
                   float* __restrict__ dout){
  __shared__ float hrow[Hn];
  const int b = blockIdx.x, tid = threadIdx.x;
  for (int i = tid; i < Hn; i += 256) hrow[i] = hf[(size_t)b*Hn + i];
  __syncthreads();
  if (tid < PRED){
    float a = fcb[tid];
    for (int k = 0; k < Hn; k++) a += hrow[k] * fcw[(size_t)k*PRED + tid];
    dout[(size_t)b*PRED + tid] = tanhf(a);
  }
  for (int i = tid; i < Hn; i += 256){
    dout[Bsz*PRED + (size_t)b*Hn + i] = hf[(size_t)b*Hn + i];
    dout[Bsz*PRED + (size_t)Bsz*Hn + (size_t)b*Hn + i] = cst[(size_t)b*Hn + i];
  }
}

extern "C" void kernel_launch(void* const* d_in, const int* in_sizes, int n_in,
                              void* d_out, int out_size, void* d_ws, size_t ws_size,
                              hipStream_t stream){
  const float* x   = (const float*)d_in[0];
  const float* W0  = (const float*)d_in[1];
  const float* b0  = (const float*)d_in[2];
  const float* W1  = (const float*)d_in[3];
  const float* b1  = (const float*)d_in[4];
  const float* fcw = (const float*)d_in[5];
  const float* fcb = (const float*)d_in[6];
  float* dout = (float*)d_out;

  char* p = (char*)d_ws;
  auto alloc = [&](size_t bytes)->void*{
    void* r = (void*)p; p += (bytes + 255) & ~(size_t)255; return r;
  };
  // base footprint ~103.5 MB (proven); +67 MB h1 ring only if workspace allows
  unsigned short* xp   = (unsigned short*)alloc((size_t)SEQn*Bsz*NUMS*2);      // 8.4 MB
  unsigned short* Wpk0 = (unsigned short*)alloc((size_t)256*36*64*8*2);        // 9.4 MB
  unsigned short* Wpk1 = (unsigned short*)alloc((size_t)256*64*64*8*2);        // 16.8 MB
  unsigned short* H0   = (unsigned short*)alloc((size_t)(SEQn+1)*BH*2);        // 67.4 MB
  float* cst = (float*)alloc((size_t)BH*4);                                    // 0.5 MB
  float* hf  = (float*)alloc((size_t)BH*4);                                    // 0.5 MB
  unsigned* bars = (unsigned*)alloc((size_t)2048*sizeof(unsigned));            // 8 KB

  const bool big = ws_size >= (size_t)176*1024*1024;   // room for write-once h1 ring?
  unsigned short* h1b;
  if (big) h1b = (unsigned short*)alloc((size_t)SEQn*BH*2);                    // 67.1 MB
  else     h1b = (unsigned short*)alloc((size_t)2*BH*2);                       // 0.5 MB

  pack_x_kernel<<<dim3(SEQn/64, NUMS/64, Bsz), dim3(256), 0, stream>>>(x, xp);
  // W0 packed K order: [h rows 128..1151 -> kst 0..31][x rows 0..127 -> kst 32..35]
  pack_w_kernel<<<dim3((256*32*64 + 255)/256), dim3(256), 0, stream>>>(W0, Wpk0, 32, 128, 36, 0);
  pack_w_kernel<<<dim3((256*4*64  + 255)/256), dim3(256), 0, stream>>>(W0, Wpk0,  4,   0, 36, 32);
  // W1: rows 0..1023 = h0-part, 1024..2047 = h1-part (natural order)
  pack_w_kernel<<<dim3((256*64*64 + 255)/256), dim3(256), 0, stream>>>(W1, Wpk1, 64, 0, 64, 0);
  zero_kernel<<<dim3((Bsz*Hn + 255)/256), dim3(256), 0, stream>>>(H0, cst, bars);

  // layer 0: ONE persistent launch, 256 flag-synced steps (K = [h 1024 | x 128])
  persist_kernel<1024, NUMS, 1152, 0, false><<<dim3(GN), dim3(512), 0, stream>>>(
      xp, H0, nullptr, Wpk0, b0, cst, nullptr, bars);

  // layer 1: ONE persistent launch (K = [h0 1024 | h1 1024])
  if (big){
    persist_kernel<1024, Hn, 2048, 1, true><<<dim3(GN), dim3(512), 0, stream>>>(
        nullptr, H0, h1b, Wpk1, b1, cst, hf, bars + 1024);
  } else {
    persist_kernel<1024, Hn, 2048, 1, false><<<dim3(GN), dim3(512), 0, stream>>>(
        nullptr, H0, h1b, Wpk1, b1, cst, hf, bars + 1024);
  }

  fc_out_kernel<<<dim3(Bsz), dim3(256), 0, stream>>>(hf, cst, fcw, fcb, dout);
}